// Round 1
// baseline (7003.926 us; speedup 1.0000x reference)
//
#include <hip/hip_runtime.h>

#define N_ROWS 32768
#define DIM 512
#define K_CODES 8192
#define BN 64
#define BK 256
#define BD 32
#define EPS 0.01f

// ---------------------------------------------------------------- e_sq
__global__ __launch_bounds__(256) void esq_kernel(const float* __restrict__ embed,
                                                  float* __restrict__ e_sq) {
    int code = blockIdx.x * 4 + (threadIdx.x >> 6);
    int lane = threadIdx.x & 63;
    const float4* row = (const float4*)(embed + (size_t)code * DIM);
    float s = 0.f;
#pragma unroll
    for (int i = 0; i < 2; ++i) {
        float4 v = row[lane + i * 64];
        s += v.x * v.x + v.y * v.y + v.z * v.z + v.w * v.w;
    }
#pragma unroll
    for (int off = 32; off > 0; off >>= 1) s += __shfl_down(s, off);
    if (lane == 0) e_sq[code] = s;
}

// ---------------------------------------------------------------- pass A: fp32 tiled scores + candidate emission
__global__ __launch_bounds__(256) void passA_kernel(const float* __restrict__ x,
                                                    const float* __restrict__ embed,
                                                    const float* __restrict__ e_sq,
                                                    unsigned int* __restrict__ cand_count,
                                                    unsigned int* __restrict__ cands,
                                                    int slots) {
    __shared__ float xs[BD][BN];
    __shared__ float es[BD][BK];
    __shared__ float bbest[BN];
    __shared__ unsigned long long smin[BN][33];  // pad col to break bank conflicts

    const int tid = threadIdx.x;
    const int tx = tid & 31, ty = tid >> 5;
    const int kb = blockIdx.x * BK;
    const int nb = blockIdx.y * BN;

    float acc[8][8];
#pragma unroll
    for (int i = 0; i < 8; ++i)
#pragma unroll
        for (int j = 0; j < 8; ++j) acc[i][j] = 0.f;

    for (int dt = 0; dt < DIM; dt += BD) {
        // x tile: [BD][BN], transposed store. thread: row = tid>>2, seg = tid&3
        {
            int row = tid >> 2, seg = tid & 3;
            const float* xp = x + (size_t)(nb + row) * DIM + dt + seg * 4;
            float4 v0 = *(const float4*)(xp);
            float4 v1 = *(const float4*)(xp + 16);
            xs[seg * 4 + 0][row] = v0.x;  xs[seg * 4 + 1][row] = v0.y;
            xs[seg * 4 + 2][row] = v0.z;  xs[seg * 4 + 3][row] = v0.w;
            xs[seg * 4 + 16][row] = v1.x; xs[seg * 4 + 17][row] = v1.y;
            xs[seg * 4 + 18][row] = v1.z; xs[seg * 4 + 19][row] = v1.w;
        }
        // e tile: thread t owns code kb+t, reads 32 dims, stores transposed (conflict-free column writes)
        {
            const float* ep = embed + (size_t)(kb + tid) * DIM + dt;
            float4 v[8];
#pragma unroll
            for (int i = 0; i < 8; ++i) v[i] = *(const float4*)(ep + i * 4);
#pragma unroll
            for (int i = 0; i < 8; ++i) {
                es[i * 4 + 0][tid] = v[i].x; es[i * 4 + 1][tid] = v[i].y;
                es[i * 4 + 2][tid] = v[i].z; es[i * 4 + 3][tid] = v[i].w;
            }
        }
        __syncthreads();
#pragma unroll
        for (int d = 0; d < BD; ++d) {
            float a[8], b[8];
            float4 a0 = *(const float4*)&xs[d][ty * 8];
            float4 a1 = *(const float4*)&xs[d][ty * 8 + 4];
            a[0] = a0.x; a[1] = a0.y; a[2] = a0.z; a[3] = a0.w;
            a[4] = a1.x; a[5] = a1.y; a[6] = a1.z; a[7] = a1.w;
#pragma unroll
            for (int j = 0; j < 8; ++j) b[j] = es[d][tx + j * 32];
#pragma unroll
            for (int i = 0; i < 8; ++i)
#pragma unroll
                for (int j = 0; j < 8; ++j) acc[i][j] = fmaf(a[i], b[j], acc[i][j]);
        }
        __syncthreads();
    }

    // scores: overwrite acc in place: score = e_sq[k] - 2*dot
    float esr[8];
#pragma unroll
    for (int j = 0; j < 8; ++j) esr[j] = e_sq[kb + tx + j * 32];
#pragma unroll
    for (int i = 0; i < 8; ++i) {
        float best = 3.4e38f;
        int bj = 0;
#pragma unroll
        for (int j = 0; j < 8; ++j) {
            acc[i][j] = fmaf(-2.f, acc[i][j], esr[j]);
            if (acc[i][j] < best) { best = acc[i][j]; bj = j; }
        }
        unsigned int bbits = __float_as_uint(best);
        unsigned int ord = (bbits & 0x80000000u) ? ~bbits : (bbits | 0x80000000u);
        unsigned int kg = (unsigned int)(tx + bj * 32);
        smin[ty * 8 + i][tx] = ((unsigned long long)ord << 32) | kg;
    }
    __syncthreads();
    if (tid < BN) {
        unsigned long long m = smin[tid][0];
#pragma unroll 4
        for (int c = 1; c < 32; ++c) {
            unsigned long long v = smin[tid][c];
            if (v < m) m = v;
        }
        unsigned int ord = (unsigned int)(m >> 32);
        unsigned int bbits = (ord & 0x80000000u) ? (ord & 0x7fffffffu) : ~ord;
        bbest[tid] = __uint_as_float(bbits);
    }
    __syncthreads();
    // emit every k within EPS of the block-local best for its row
#pragma unroll
    for (int i = 0; i < 8; ++i) {
        int row = ty * 8 + i;
        float thr = bbest[row] + EPS;
#pragma unroll
        for (int j = 0; j < 8; ++j) {
            if (acc[i][j] <= thr) {
                unsigned int slot = atomicAdd(&cand_count[nb + row], 1u);
                if (slot < (unsigned)slots)
                    cands[(size_t)(nb + row) * slots + slot] = (unsigned)(kb + tx + j * 32);
            }
        }
    }
}

// ---------------------------------------------------------------- pass B: f64 exact re-score + gather + STE + loss
__global__ __launch_bounds__(256) void refine_kernel(const float* __restrict__ x,
                                                     const float* __restrict__ embed,
                                                     const unsigned int* __restrict__ cand_count,
                                                     const unsigned int* __restrict__ cands,
                                                     int slots,
                                                     float* __restrict__ out_q,
                                                     float* __restrict__ out_ind,
                                                     double* __restrict__ loss_acc) {
    __shared__ double s_score[64];
    __shared__ unsigned int s_idx[64];
    __shared__ int s_best;
    __shared__ float s_ls[4];

    const int row = blockIdx.x;
    const int tid = threadIdx.x;
    const int wave = tid >> 6, lane = tid & 63;
    int c = (int)cand_count[row];
    if (c > slots) c = slots;
    if (c < 1) c = 1;

    const float4* xp = (const float4*)(x + (size_t)row * DIM);
    for (int ci = wave; ci < c; ci += 4) {
        unsigned int k = cands[(size_t)row * slots + ci] & (K_CODES - 1);
        const float4* ep = (const float4*)(embed + (size_t)k * DIM);
        double s = 0.0;
#pragma unroll
        for (int i = 0; i < 2; ++i) {
            float4 ev = ep[lane + i * 64];
            float4 xv = xp[lane + i * 64];
            s += (double)ev.x * ((double)ev.x - 2.0 * (double)xv.x);
            s += (double)ev.y * ((double)ev.y - 2.0 * (double)xv.y);
            s += (double)ev.z * ((double)ev.z - 2.0 * (double)xv.z);
            s += (double)ev.w * ((double)ev.w - 2.0 * (double)xv.w);
        }
#pragma unroll
        for (int off = 32; off > 0; off >>= 1) s += __shfl_down(s, off);
        if (lane == 0) { s_score[ci] = s; s_idx[ci] = k; }
    }
    __syncthreads();
    if (tid == 0) {
        double best = s_score[0];
        unsigned int bidx = s_idx[0];
        for (int ci = 1; ci < c; ++ci) {
            double sv = s_score[ci];
            unsigned int k = s_idx[ci];
            if (sv < best || (sv == best && k < bidx)) { best = sv; bidx = k; }
        }
        s_best = (int)bidx;
        out_ind[row] = (float)bidx;  // harness reads flat f32; indices exact in f32
    }
    __syncthreads();
    const int k = s_best;
    // quantize + STE + loss: 512 elems / 256 threads = float2 each
    const float2* x2 = (const float2*)(x + (size_t)row * DIM);
    const float2* e2 = (const float2*)(embed + (size_t)k * DIM);
    float2* o2 = (float2*)(out_q + (size_t)row * DIM);
    float2 xv = x2[tid], ev = e2[tid];
    float2 o;
    o.x = xv.x + (ev.x - xv.x);  // mimic reference STE rounding
    o.y = xv.y + (ev.y - xv.y);
    o2[tid] = o;
    float dx = ev.x - xv.x, dy = ev.y - xv.y;
    float ls = dx * dx + dy * dy;
#pragma unroll
    for (int off = 32; off > 0; off >>= 1) ls += __shfl_down(ls, off);
    if (lane == 0) s_ls[wave] = ls;
    __syncthreads();
    if (tid == 0) atomicAdd(loss_acc, (double)(s_ls[0] + s_ls[1] + s_ls[2] + s_ls[3]));
}

// ---------------------------------------------------------------- finalize loss
__global__ void finalize_kernel(const double* __restrict__ loss_acc, float* __restrict__ out_loss) {
    *out_loss = (float)(*loss_acc / ((double)N_ROWS * (double)DIM));
}

// ---------------------------------------------------------------- launch
extern "C" void kernel_launch(void* const* d_in, const int* in_sizes, int n_in,
                              void* d_out, int out_size, void* d_ws, size_t ws_size,
                              hipStream_t stream) {
    const float* x = (const float*)d_in[0];
    const float* embed = (const float*)d_in[1];
    float* out = (float*)d_out;
    float* out_q = out;
    float* out_ind = out + (size_t)N_ROWS * DIM;
    float* out_loss = out_ind + N_ROWS;

    char* ws = (char*)d_ws;
    // layout: e_sq [K f32] | counts [N u32] | loss [f64] | cands [N*slots u32]
    float* e_sq = (float*)ws;
    unsigned int* counts = (unsigned int*)(ws + (size_t)K_CODES * 4);
    double* loss_acc = (double*)(ws + (size_t)K_CODES * 4 + (size_t)N_ROWS * 4);
    unsigned int* cands = (unsigned int*)(ws + (size_t)K_CODES * 4 + (size_t)N_ROWS * 4 + 8);
    size_t fixed = (size_t)K_CODES * 4 + (size_t)N_ROWS * 4 + 8;
    int slots = 40;
    if (ws_size > fixed) {
        size_t avail = (ws_size - fixed) / ((size_t)N_ROWS * 4);
        if (avail < (size_t)slots) slots = (int)avail;
    }
    if (slots < 2) slots = 2;

    hipMemsetAsync(counts, 0, (size_t)N_ROWS * 4, stream);
    hipMemsetAsync(loss_acc, 0, 8, stream);
    esq_kernel<<<K_CODES / 4, 256, 0, stream>>>(embed, e_sq);
    passA_kernel<<<dim3(K_CODES / BK, N_ROWS / BN), 256, 0, stream>>>(x, embed, e_sq, counts, cands, slots);
    refine_kernel<<<N_ROWS, 256, 0, stream>>>(x, embed, counts, cands, slots, out_q, out_ind, loss_acc);
    finalize_kernel<<<1, 1, 0, stream>>>(loss_acc, out_loss);
}

// Round 2
// 1635.120 us; speedup vs baseline: 4.2834x; 4.2834x over previous
//
#include <hip/hip_runtime.h>

#define N_ROWS 32768
#define DIM 512
#define K_CODES 8192

// ---- MFMA pass geometry
#define SEGS 4
#define SEGC (K_CODES / SEGS)   // 2048 codes per segment
#define TM 128
#define TN 128
#define NT (SEGC / TN)          // 16 n-tiles per block
#define BKK 32
#define EPS_MFMA 1.5f
#define SLOTS_MFMA 48

// ---- fp32 fallback geometry (round-1 kernel)
#define BN 64
#define BK 256
#define BD 32
#define EPS_FP32 0.01f

typedef __attribute__((ext_vector_type(8))) short bf16x8;
typedef __attribute__((ext_vector_type(4))) float f32x4;
typedef __attribute__((ext_vector_type(8))) unsigned short ushort8;

__device__ inline unsigned int ord_f32(float f) {
    unsigned int u = __float_as_uint(f);
    return (u & 0x80000000u) ? ~u : (u | 0x80000000u);
}
__device__ inline float unord_f32(unsigned int u) {
    unsigned int b = (u & 0x80000000u) ? (u & 0x7fffffffu) : ~u;
    return __uint_as_float(b);
}
__device__ inline unsigned short f2bf_rn(float f) {
    unsigned int u = __float_as_uint(f);
    u += 0x7fffu + ((u >> 16) & 1u);
    return (unsigned short)(u >> 16);
}

// ---------------------------------------------------------------- e_sq (fp32 exact-ish)
__global__ __launch_bounds__(256) void esq_kernel(const float* __restrict__ embed,
                                                  float* __restrict__ e_sq) {
    int code = blockIdx.x * 4 + (threadIdx.x >> 6);
    int lane = threadIdx.x & 63;
    const float4* row = (const float4*)(embed + (size_t)code * DIM);
    float s = 0.f;
#pragma unroll
    for (int i = 0; i < 2; ++i) {
        float4 v = row[lane + i * 64];
        s += v.x * v.x + v.y * v.y + v.z * v.z + v.w * v.w;
    }
#pragma unroll
    for (int off = 32; off > 0; off >>= 1) s += __shfl_down(s, off);
    if (lane == 0) e_sq[code] = s;
}

// ---------------------------------------------------------------- fp32 -> bf16 conversion (vectorized)
__global__ __launch_bounds__(256) void cvt_kernel(const float* __restrict__ in,
                                                  unsigned short* __restrict__ out, int n8) {
    int i = blockIdx.x * 256 + threadIdx.x;
    if (i >= n8) return;
    const float4* p = (const float4*)in;
    float4 v0 = p[(size_t)i * 2], v1 = p[(size_t)i * 2 + 1];
    ushort8 o;
    o[0] = f2bf_rn(v0.x); o[1] = f2bf_rn(v0.y); o[2] = f2bf_rn(v0.z); o[3] = f2bf_rn(v0.w);
    o[4] = f2bf_rn(v1.x); o[5] = f2bf_rn(v1.y); o[6] = f2bf_rn(v1.z); o[7] = f2bf_rn(v1.w);
    ((ushort8*)out)[i] = o;
}

// ---------------------------------------------------------------- pass A (bf16 MFMA): scores + running-min candidate emission
__global__ __launch_bounds__(256) void passA_mfma_kernel(const unsigned short* __restrict__ xbf,
                                                         const unsigned short* __restrict__ ebf,
                                                         const float* __restrict__ e_sq,
                                                         unsigned int* __restrict__ cand_count,
                                                         unsigned int* __restrict__ cands,
                                                         int slots) {
    __shared__ unsigned short As[TM * BKK];   // 8 KB, row-major [128][32]
    __shared__ unsigned short Bs[TN * BKK];   // 8 KB
    __shared__ float esq_s[SEGC];             // 8 KB
    __shared__ unsigned int row_best[TM];     // running per-row min (ordered bits)

    const int tid = threadIdx.x;
    const int lane = tid & 63;
    const int wv = tid >> 6;
    const int wm = wv >> 1, wn = wv & 1;
    const int l15 = lane & 15, l4 = lane >> 4;
    const int row0 = blockIdx.y * TM;
    const int seg0 = blockIdx.x * SEGC;

    for (int i = tid; i < SEGC; i += 256) esq_s[i] = e_sq[seg0 + i];
    if (tid < TM) row_best[tid] = 0xFFFFFFFFu;

    // staging chunk map: chunk c covers row c>>2, bf16 quarter (c&3)*8; LDS byte = c*16
    const int c0 = tid, c1 = tid + 256;
    const size_t a0r = (size_t)(row0 + (c0 >> 2)), a1r = (size_t)(row0 + (c1 >> 2));
    const int q0 = (c0 & 3) * 8, q1 = (c1 & 3) * 8;

    __syncthreads();

    for (int nt = 0; nt < NT; ++nt) {
        const int code0 = seg0 + nt * TN;
        f32x4 acc[4][4];
#pragma unroll
        for (int m = 0; m < 4; ++m)
#pragma unroll
            for (int n = 0; n < 4; ++n) acc[m][n] = f32x4{0.f, 0.f, 0.f, 0.f};

        for (int kt = 0; kt < DIM; kt += BKK) {
            const unsigned short* ga0 = xbf + a0r * DIM + kt + q0;
            const unsigned short* ga1 = xbf + a1r * DIM + kt + q1;
            const unsigned short* gb0 = ebf + (size_t)(code0 + (c0 >> 2)) * DIM + kt + q0;
            const unsigned short* gb1 = ebf + (size_t)(code0 + (c1 >> 2)) * DIM + kt + q1;
            __builtin_amdgcn_global_load_lds((const __attribute__((address_space(1))) void*)ga0,
                                             (__attribute__((address_space(3))) void*)&As[c0 * 8], 16, 0, 0);
            __builtin_amdgcn_global_load_lds((const __attribute__((address_space(1))) void*)ga1,
                                             (__attribute__((address_space(3))) void*)&As[c1 * 8], 16, 0, 0);
            __builtin_amdgcn_global_load_lds((const __attribute__((address_space(1))) void*)gb0,
                                             (__attribute__((address_space(3))) void*)&Bs[c0 * 8], 16, 0, 0);
            __builtin_amdgcn_global_load_lds((const __attribute__((address_space(1))) void*)gb1,
                                             (__attribute__((address_space(3))) void*)&Bs[c1 * 8], 16, 0, 0);
            __syncthreads();  // compiler drains vmcnt(0) before barrier -> tile visible
            bf16x8 af[4], bfr[4];
#pragma unroll
            for (int m = 0; m < 4; ++m)
                af[m] = *(const bf16x8*)&As[(wm * 64 + m * 16 + l15) * BKK + l4 * 8];
#pragma unroll
            for (int n = 0; n < 4; ++n)
                bfr[n] = *(const bf16x8*)&Bs[(wn * 64 + n * 16 + l15) * BKK + l4 * 8];
#pragma unroll
            for (int m = 0; m < 4; ++m)
#pragma unroll
                for (int n = 0; n < 4; ++n)
                    acc[m][n] = __builtin_amdgcn_mfma_f32_16x16x32_bf16(af[m], bfr[n], acc[m][n], 0, 0, 0);
            __syncthreads();  // all reads done before next stage overwrites
        }

        // ---- epilogue: score = e_sq - 2*dot; C frag: row=(lane>>4)*4+reg, col=lane&15
        float esr[4];
#pragma unroll
        for (int n = 0; n < 4; ++n) esr[n] = esq_s[nt * TN + wn * 64 + n * 16 + l15];
        float rv[4][4];
#pragma unroll
        for (int m = 0; m < 4; ++m)
#pragma unroll
            for (int r = 0; r < 4; ++r) rv[m][r] = 3.4e38f;
#pragma unroll
        for (int m = 0; m < 4; ++m)
#pragma unroll
            for (int n = 0; n < 4; ++n)
#pragma unroll
                for (int r = 0; r < 4; ++r) {
                    float s = fmaf(-2.f, acc[m][n][r], esr[n]);
                    acc[m][n][r] = s;
                    rv[m][r] = fminf(rv[m][r], s);
                }
        // reduce across the 16 cols (low-4 lane bits)
#pragma unroll
        for (int d = 1; d < 16; d <<= 1)
#pragma unroll
            for (int m = 0; m < 4; ++m)
#pragma unroll
                for (int r = 0; r < 4; ++r) rv[m][r] = fminf(rv[m][r], __shfl_xor(rv[m][r], d));
        if (l15 == 0) {
#pragma unroll
            for (int m = 0; m < 4; ++m)
#pragma unroll
                for (int r = 0; r < 4; ++r)
                    atomicMin(&row_best[wm * 64 + m * 16 + l4 * 4 + r], ord_f32(rv[m][r]));
        }
        __syncthreads();
        // emit candidates within EPS of the running (tiles-so-far) per-row best
#pragma unroll
        for (int m = 0; m < 4; ++m)
#pragma unroll
            for (int r = 0; r < 4; ++r) {
                const int lrow = wm * 64 + m * 16 + l4 * 4 + r;
                const float th = unord_f32(row_best[lrow]) + EPS_MFMA;
                const int grow = row0 + lrow;
#pragma unroll
                for (int n = 0; n < 4; ++n) {
                    if (acc[m][n][r] <= th) {
                        unsigned int slot = atomicAdd(&cand_count[grow], 1u);
                        if (slot < (unsigned)slots)
                            cands[(size_t)grow * slots + slot] = (unsigned)(code0 + wn * 64 + n * 16 + l15);
                    }
                }
            }
        // no barrier needed: next tile's k-loop barriers order row_best reads vs future atomicMin
    }
}

// ---------------------------------------------------------------- pass A fp32 fallback (round-1 kernel, unchanged)
__global__ __launch_bounds__(256) void passA_fp32_kernel(const float* __restrict__ x,
                                                         const float* __restrict__ embed,
                                                         const float* __restrict__ e_sq,
                                                         unsigned int* __restrict__ cand_count,
                                                         unsigned int* __restrict__ cands,
                                                         int slots) {
    __shared__ float xs[BD][BN];
    __shared__ float es[BD][BK];
    __shared__ float bbest[BN];
    __shared__ unsigned long long smin[BN][33];

    const int tid = threadIdx.x;
    const int tx = tid & 31, ty = tid >> 5;
    const int kb = blockIdx.x * BK;
    const int nb = blockIdx.y * BN;

    float acc[8][8];
#pragma unroll
    for (int i = 0; i < 8; ++i)
#pragma unroll
        for (int j = 0; j < 8; ++j) acc[i][j] = 0.f;

    for (int dt = 0; dt < DIM; dt += BD) {
        {
            int row = tid >> 2, seg = tid & 3;
            const float* xp = x + (size_t)(nb + row) * DIM + dt + seg * 4;
            float4 v0 = *(const float4*)(xp);
            float4 v1 = *(const float4*)(xp + 16);
            xs[seg * 4 + 0][row] = v0.x;  xs[seg * 4 + 1][row] = v0.y;
            xs[seg * 4 + 2][row] = v0.z;  xs[seg * 4 + 3][row] = v0.w;
            xs[seg * 4 + 16][row] = v1.x; xs[seg * 4 + 17][row] = v1.y;
            xs[seg * 4 + 18][row] = v1.z; xs[seg * 4 + 19][row] = v1.w;
        }
        {
            const float* ep = embed + (size_t)(kb + tid) * DIM + dt;
            float4 v[8];
#pragma unroll
            for (int i = 0; i < 8; ++i) v[i] = *(const float4*)(ep + i * 4);
#pragma unroll
            for (int i = 0; i < 8; ++i) {
                es[i * 4 + 0][tid] = v[i].x; es[i * 4 + 1][tid] = v[i].y;
                es[i * 4 + 2][tid] = v[i].z; es[i * 4 + 3][tid] = v[i].w;
            }
        }
        __syncthreads();
#pragma unroll
        for (int d = 0; d < BD; ++d) {
            float a[8], b[8];
            float4 a0 = *(const float4*)&xs[d][ty * 8];
            float4 a1 = *(const float4*)&xs[d][ty * 8 + 4];
            a[0] = a0.x; a[1] = a0.y; a[2] = a0.z; a[3] = a0.w;
            a[4] = a1.x; a[5] = a1.y; a[6] = a1.z; a[7] = a1.w;
#pragma unroll
            for (int j = 0; j < 8; ++j) b[j] = es[d][tx + j * 32];
#pragma unroll
            for (int i = 0; i < 8; ++i)
#pragma unroll
                for (int j = 0; j < 8; ++j) acc[i][j] = fmaf(a[i], b[j], acc[i][j]);
        }
        __syncthreads();
    }

    float esr[8];
#pragma unroll
    for (int j = 0; j < 8; ++j) esr[j] = e_sq[kb + tx + j * 32];
#pragma unroll
    for (int i = 0; i < 8; ++i) {
        float best = 3.4e38f;
#pragma unroll
        for (int j = 0; j < 8; ++j) {
            acc[i][j] = fmaf(-2.f, acc[i][j], esr[j]);
            if (acc[i][j] < best) best = acc[i][j];
        }
        unsigned int bbits = __float_as_uint(best);
        unsigned int ord = (bbits & 0x80000000u) ? ~bbits : (bbits | 0x80000000u);
        smin[ty * 8 + i][tx] = ((unsigned long long)ord << 32);
    }
    __syncthreads();
    if (tid < BN) {
        unsigned long long m = smin[tid][0];
#pragma unroll 4
        for (int c = 1; c < 32; ++c) {
            unsigned long long v = smin[tid][c];
            if (v < m) m = v;
        }
        unsigned int ord = (unsigned int)(m >> 32);
        unsigned int bbits = (ord & 0x80000000u) ? (ord & 0x7fffffffu) : ~ord;
        bbest[tid] = __uint_as_float(bbits);
    }
    __syncthreads();
#pragma unroll
    for (int i = 0; i < 8; ++i) {
        int row = ty * 8 + i;
        float thr = bbest[row] + EPS_FP32;
#pragma unroll
        for (int j = 0; j < 8; ++j) {
            if (acc[i][j] <= thr) {
                unsigned int slot = atomicAdd(&cand_count[nb + row], 1u);
                if (slot < (unsigned)slots)
                    cands[(size_t)(nb + row) * slots + slot] = (unsigned)(kb + tx + j * 32);
            }
        }
    }
}

// ---------------------------------------------------------------- pass B: f64 exact re-score (+ brute-force overflow net) + gather + STE + loss
__global__ __launch_bounds__(256) void refine_kernel(const float* __restrict__ x,
                                                     const float* __restrict__ embed,
                                                     const unsigned int* __restrict__ cand_count,
                                                     const unsigned int* __restrict__ cands,
                                                     int slots,
                                                     float* __restrict__ out_q,
                                                     float* __restrict__ out_ind,
                                                     double* __restrict__ loss_acc) {
    __shared__ double s_score[64];
    __shared__ unsigned int s_idx[64];
    __shared__ int s_best;
    __shared__ float s_ls[4];

    const int row = blockIdx.x;
    const int tid = threadIdx.x;
    const int wave = tid >> 6, lane = tid & 63;
    const unsigned int craw = cand_count[row];
    const float4* xp = (const float4*)(x + (size_t)row * DIM);

    if (craw <= (unsigned)slots) {
        int c = (int)craw;
        if (c < 1) c = 1;
        for (int ci = wave; ci < c; ci += 4) {
            unsigned int k = cands[(size_t)row * slots + ci] & (K_CODES - 1);
            const float4* ep = (const float4*)(embed + (size_t)k * DIM);
            double s = 0.0;
#pragma unroll
            for (int i = 0; i < 2; ++i) {
                float4 ev = ep[lane + i * 64];
                float4 xv = xp[lane + i * 64];
                s += (double)ev.x * ((double)ev.x - 2.0 * (double)xv.x);
                s += (double)ev.y * ((double)ev.y - 2.0 * (double)xv.y);
                s += (double)ev.z * ((double)ev.z - 2.0 * (double)xv.z);
                s += (double)ev.w * ((double)ev.w - 2.0 * (double)xv.w);
            }
#pragma unroll
            for (int off = 32; off > 0; off >>= 1) s += __shfl_down(s, off);
            if (lane == 0) { s_score[ci] = s; s_idx[ci] = k; }
        }
        __syncthreads();
        if (tid == 0) {
            double best = s_score[0];
            unsigned int bidx = s_idx[0];
            for (int ci = 1; ci < c; ++ci) {
                double sv = s_score[ci];
                unsigned int k = s_idx[ci];
                if (sv < best || (sv == best && k < bidx)) { best = sv; bidx = k; }
            }
            s_best = (int)bidx;
            out_ind[row] = (float)bidx;
        }
    } else {
        // overflow safety net: exact f64 scan over all codes
        double wbest = 1e300;
        int wbidx = 0;
        for (int k = wave; k < K_CODES; k += 4) {
            const float4* ep = (const float4*)(embed + (size_t)k * DIM);
            double s = 0.0;
#pragma unroll
            for (int i = 0; i < 2; ++i) {
                float4 ev = ep[lane + i * 64];
                float4 xv = xp[lane + i * 64];
                s += (double)ev.x * ((double)ev.x - 2.0 * (double)xv.x);
                s += (double)ev.y * ((double)ev.y - 2.0 * (double)xv.y);
                s += (double)ev.z * ((double)ev.z - 2.0 * (double)xv.z);
                s += (double)ev.w * ((double)ev.w - 2.0 * (double)xv.w);
            }
#pragma unroll
            for (int off = 32; off > 0; off >>= 1) s += __shfl_down(s, off);
            if (lane == 0 && s < wbest) { wbest = s; wbidx = k; }
        }
        if (lane == 0) { s_score[wave] = wbest; s_idx[wave] = (unsigned)wbidx; }
        __syncthreads();
        if (tid == 0) {
            double best = s_score[0];
            unsigned int bidx = s_idx[0];
            for (int w = 1; w < 4; ++w) {
                if (s_score[w] < best || (s_score[w] == best && s_idx[w] < bidx)) {
                    best = s_score[w]; bidx = s_idx[w];
                }
            }
            s_best = (int)bidx;
            out_ind[row] = (float)bidx;
        }
    }
    __syncthreads();
    const int k = s_best;
    const float2* x2 = (const float2*)(x + (size_t)row * DIM);
    const float2* e2 = (const float2*)(embed + (size_t)k * DIM);
    float2* o2 = (float2*)(out_q + (size_t)row * DIM);
    float2 xv = x2[tid], ev = e2[tid];
    float2 o;
    o.x = xv.x + (ev.x - xv.x);
    o.y = xv.y + (ev.y - xv.y);
    o2[tid] = o;
    float dx = ev.x - xv.x, dy = ev.y - xv.y;
    float ls = dx * dx + dy * dy;
#pragma unroll
    for (int off = 32; off > 0; off >>= 1) ls += __shfl_down(ls, off);
    if (lane == 0) s_ls[wave] = ls;
    __syncthreads();
    if (tid == 0) atomicAdd(loss_acc, (double)(s_ls[0] + s_ls[1] + s_ls[2] + s_ls[3]));
}

// ---------------------------------------------------------------- finalize loss
__global__ void finalize_kernel(const double* __restrict__ loss_acc, float* __restrict__ out_loss) {
    *out_loss = (float)(*loss_acc / ((double)N_ROWS * (double)DIM));
}

// ---------------------------------------------------------------- launch
extern "C" void kernel_launch(void* const* d_in, const int* in_sizes, int n_in,
                              void* d_out, int out_size, void* d_ws, size_t ws_size,
                              hipStream_t stream) {
    const float* x = (const float*)d_in[0];
    const float* embed = (const float*)d_in[1];
    float* out = (float*)d_out;
    float* out_q = out;
    float* out_ind = out + (size_t)N_ROWS * DIM;
    float* out_loss = out_ind + N_ROWS;

    char* ws = (char*)d_ws;
    double* loss_acc = (double*)ws;                                   // 16 B (padded)
    float* e_sq = (float*)(ws + 16);                                  // 32768 B
    unsigned int* counts = (unsigned int*)(ws + 16 + 32768);          // 131072 B
    char* dyn = ws + 16 + 32768 + 131072;
    size_t fixed = (size_t)16 + 32768 + 131072;
    size_t dyn_avail = ws_size > fixed ? ws_size - fixed : 0;

    const size_t xbf_b = (size_t)N_ROWS * DIM * 2;   // 33.5 MB
    const size_t ebf_b = (size_t)K_CODES * DIM * 2;  // 8.4 MB
    const size_t need_mfma = xbf_b + ebf_b + (size_t)N_ROWS * SLOTS_MFMA * 4;

    hipMemsetAsync(counts, 0, (size_t)N_ROWS * 4, stream);
    hipMemsetAsync(loss_acc, 0, 16, stream);
    esq_kernel<<<K_CODES / 4, 256, 0, stream>>>(embed, e_sq);

    if (dyn_avail >= need_mfma) {
        unsigned short* xbf = (unsigned short*)dyn;
        unsigned short* ebf = (unsigned short*)(dyn + xbf_b);
        unsigned int* cands = (unsigned int*)(dyn + xbf_b + ebf_b);
        cvt_kernel<<<(N_ROWS * DIM / 8 + 255) / 256, 256, 0, stream>>>(x, xbf, N_ROWS * DIM / 8);
        cvt_kernel<<<(K_CODES * DIM / 8 + 255) / 256, 256, 0, stream>>>(embed, ebf, K_CODES * DIM / 8);
        passA_mfma_kernel<<<dim3(SEGS, N_ROWS / TM), 256, 0, stream>>>(xbf, ebf, e_sq, counts, cands, SLOTS_MFMA);
        refine_kernel<<<N_ROWS, 256, 0, stream>>>(x, embed, counts, cands, SLOTS_MFMA, out_q, out_ind, loss_acc);
    } else {
        unsigned int* cands = (unsigned int*)dyn;
        int slots = 40;
        size_t avail = dyn_avail / ((size_t)N_ROWS * 4);
        if (avail < (size_t)slots) slots = (int)avail;
        if (slots < 2) slots = 2;
        passA_fp32_kernel<<<dim3(K_CODES / BK, N_ROWS / BN), 256, 0, stream>>>(x, embed, e_sq, counts, cands, slots);
        refine_kernel<<<N_ROWS, 256, 0, stream>>>(x, embed, counts, cands, slots, out_q, out_ind, loss_acc);
    }
    finalize_kernel<<<1, 1, 0, stream>>>(loss_acc, out_loss);
}

// Round 3
// 1165.676 us; speedup vs baseline: 6.0085x; 1.4027x over previous
//
#include <hip/hip_runtime.h>

#define N_ROWS 32768
#define DIM 512
#define K_CODES 8192

// ---- MFMA pass geometry: 256x256 tile, BK=32, 8 waves, double-buffered
#define TM2 256
#define TN2 256
#define BK2 32
#define NKT (DIM / BK2)      // 16 K-tiles
#define EPS_MFMA 1.5f
#define QMARG 2.2f           // covers 19-bit score quantization (step <= 2.0 for scores < 2048)
#define SLOTS 48

// ---- fp32 fallback geometry (round-1 kernel)
#define BN 64
#define BK 256
#define BD 32

typedef __attribute__((ext_vector_type(8))) short bf16x8;
typedef __attribute__((ext_vector_type(4))) float f32x4;
typedef __attribute__((ext_vector_type(8))) unsigned short ushort8;

__device__ inline unsigned int ord_f32(float f) {
    unsigned int u = __float_as_uint(f);
    return (u & 0x80000000u) ? ~u : (u | 0x80000000u);
}
__device__ inline float unord_f32(unsigned int u) {
    unsigned int b = (u & 0x80000000u) ? (u & 0x7fffffffu) : ~u;
    return __uint_as_float(b);
}
__device__ inline unsigned short f2bf_rn(float f) {
    unsigned int u = __float_as_uint(f);
    u += 0x7fffu + ((u >> 16) & 1u);
    return (unsigned short)(u >> 16);
}

// ---------------------------------------------------------------- e_sq
__global__ __launch_bounds__(256) void esq_kernel(const float* __restrict__ embed,
                                                  float* __restrict__ e_sq) {
    int code = blockIdx.x * 4 + (threadIdx.x >> 6);
    int lane = threadIdx.x & 63;
    const float4* row = (const float4*)(embed + (size_t)code * DIM);
    float s = 0.f;
#pragma unroll
    for (int i = 0; i < 2; ++i) {
        float4 v = row[lane + i * 64];
        s += v.x * v.x + v.y * v.y + v.z * v.z + v.w * v.w;
    }
#pragma unroll
    for (int off = 32; off > 0; off >>= 1) s += __shfl_down(s, off);
    if (lane == 0) e_sq[code] = s;
}

// ---------------------------------------------------------------- fp32 -> bf16
__global__ __launch_bounds__(256) void cvt_kernel(const float* __restrict__ in,
                                                  unsigned short* __restrict__ out, int n8) {
    int i = blockIdx.x * 256 + threadIdx.x;
    if (i >= n8) return;
    const float4* p = (const float4*)in;
    float4 v0 = p[(size_t)i * 2], v1 = p[(size_t)i * 2 + 1];
    ushort8 o;
    o[0] = f2bf_rn(v0.x); o[1] = f2bf_rn(v0.y); o[2] = f2bf_rn(v0.z); o[3] = f2bf_rn(v0.w);
    o[4] = f2bf_rn(v1.x); o[5] = f2bf_rn(v1.y); o[6] = f2bf_rn(v1.z); o[7] = f2bf_rn(v1.w);
    ((ushort8*)out)[i] = o;
}

// ---------------------------------------------------------------- pass A: 256x256 2-phase dbuf MFMA GEMM + candidate emission
__global__ __launch_bounds__(512) void passA2_kernel(const unsigned short* __restrict__ xbf,
                                                     const unsigned short* __restrict__ ebf,
                                                     const float* __restrict__ e_sq,
                                                     unsigned int* __restrict__ cand_count,
                                                     unsigned int* __restrict__ cands) {
    __shared__ __align__(16) unsigned short As[2][TM2 * BK2];  // 2 x 16 KB
    __shared__ __align__(16) unsigned short Bs[2][TN2 * BK2];  // 2 x 16 KB

    const int tid = threadIdx.x;
    const int lane = tid & 63;
    const int wv = tid >> 6;              // 8 waves: 2 (M) x 4 (N)
    const int wm = wv >> 2, wn = wv & 3;
    const int l15 = lane & 15, l4 = lane >> 4;
    const int row0 = blockIdx.y * TM2;
    const int col0 = blockIdx.x * TN2;

    // staging chunk map: chunk c (of 1024 per matrix) -> row c>>2, k-quarter (c&3)*8, LDS byte c*16
    const int c0 = tid, c1 = tid + 512;
    const unsigned short* xr0 = xbf + (size_t)(row0 + (c0 >> 2)) * DIM + (c0 & 3) * 8;
    const unsigned short* xr1 = xbf + (size_t)(row0 + (c1 >> 2)) * DIM + (c1 & 3) * 8;
    const unsigned short* er0 = ebf + (size_t)(col0 + (c0 >> 2)) * DIM + (c0 & 3) * 8;
    const unsigned short* er1 = ebf + (size_t)(col0 + (c1 >> 2)) * DIM + (c1 & 3) * 8;

    f32x4 acc[8][4];
#pragma unroll
    for (int m = 0; m < 8; ++m)
#pragma unroll
        for (int n = 0; n < 4; ++n) acc[m][n] = f32x4{0.f, 0.f, 0.f, 0.f};

#define STAGE(buf, kt)                                                                              \
    do {                                                                                            \
        __builtin_amdgcn_global_load_lds((const __attribute__((address_space(1))) void*)(xr0 + (kt)),\
                                         (__attribute__((address_space(3))) void*)&As[buf][c0 * 8], 16, 0, 0); \
        __builtin_amdgcn_global_load_lds((const __attribute__((address_space(1))) void*)(xr1 + (kt)),\
                                         (__attribute__((address_space(3))) void*)&As[buf][c1 * 8], 16, 0, 0); \
        __builtin_amdgcn_global_load_lds((const __attribute__((address_space(1))) void*)(er0 + (kt)),\
                                         (__attribute__((address_space(3))) void*)&Bs[buf][c0 * 8], 16, 0, 0); \
        __builtin_amdgcn_global_load_lds((const __attribute__((address_space(1))) void*)(er1 + (kt)),\
                                         (__attribute__((address_space(3))) void*)&Bs[buf][c1 * 8], 16, 0, 0); \
    } while (0)

    STAGE(0, 0);
    __syncthreads();
    int buf = 0;
    for (int kt = 0; kt < NKT; ++kt) {
        if (kt + 1 < NKT) STAGE(buf ^ 1, (kt + 1) * BK2);  // overlap next-tile stage with compute
        bf16x8 af[8], bfr[4];
#pragma unroll
        for (int m = 0; m < 8; ++m)
            af[m] = *(const bf16x8*)&As[buf][(wm * 128 + m * 16 + l15) * BK2 + l4 * 8];
#pragma unroll
        for (int n = 0; n < 4; ++n)
            bfr[n] = *(const bf16x8*)&Bs[buf][(wn * 64 + n * 16 + l15) * BK2 + l4 * 8];
#pragma unroll
        for (int m = 0; m < 8; ++m)
#pragma unroll
            for (int n = 0; n < 4; ++n)
                acc[m][n] = __builtin_amdgcn_mfma_f32_16x16x32_bf16(af[m], bfr[n], acc[m][n], 0, 0, 0);
        __syncthreads();  // drains vmcnt+lgkm: staged tile visible, reads done before overwrite
        buf ^= 1;
    }
#undef STAGE

    // ---- epilogue (once per block). As is dead now -> alias row_min onto it.
    unsigned int* row_min = (unsigned int*)&As[0][0];

    float esr[4];
#pragma unroll
    for (int n = 0; n < 4; ++n) esr[n] = e_sq[col0 + wn * 64 + n * 16 + l15];

    float rv[8][4];
#pragma unroll
    for (int m = 0; m < 8; ++m)
#pragma unroll
        for (int r = 0; r < 4; ++r) rv[m][r] = 3.4e38f;
#pragma unroll
    for (int m = 0; m < 8; ++m)
#pragma unroll
        for (int n = 0; n < 4; ++n)
#pragma unroll
            for (int r = 0; r < 4; ++r) {
                float s = fmaf(-2.f, acc[m][n][r], esr[n]);
                acc[m][n][r] = s;
                rv[m][r] = fminf(rv[m][r], s);
            }
    // reduce over the 16 columns held across l15
#pragma unroll
    for (int d = 1; d < 16; d <<= 1)
#pragma unroll
        for (int m = 0; m < 8; ++m)
#pragma unroll
            for (int r = 0; r < 4; ++r) rv[m][r] = fminf(rv[m][r], __shfl_xor(rv[m][r], d));

    if (tid < TM2) row_min[tid] = 0xFFFFFFFFu;
    __syncthreads();
    if (l15 == 0) {
#pragma unroll
        for (int m = 0; m < 8; ++m)
#pragma unroll
            for (int r = 0; r < 4; ++r)
                atomicMin(&row_min[wm * 128 + m * 16 + l4 * 4 + r], ord_f32(rv[m][r]));
    }
    __syncthreads();
    // emit candidates within EPS of the block-local per-row min, packed (qscore | code)
#pragma unroll
    for (int m = 0; m < 8; ++m)
#pragma unroll
        for (int r = 0; r < 4; ++r) {
            const int lrow = wm * 128 + m * 16 + l4 * 4 + r;
            const float th = unord_f32(row_min[lrow]) + EPS_MFMA;
            const int grow = row0 + lrow;
#pragma unroll
            for (int n = 0; n < 4; ++n) {
                if (acc[m][n][r] <= th) {
                    unsigned int slot = atomicAdd(&cand_count[grow], 1u);
                    if (slot < SLOTS) {
                        unsigned int code = (unsigned)(col0 + wn * 64 + n * 16 + l15);
                        cands[(size_t)grow * SLOTS + slot] =
                            (ord_f32(acc[m][n][r]) & 0xFFFFE000u) | code;
                    }
                }
            }
        }
}

// ---------------------------------------------------------------- fp32 fallback pass A (emits packed keys)
__global__ __launch_bounds__(256) void passA_fp32_kernel(const float* __restrict__ x,
                                                         const float* __restrict__ embed,
                                                         const float* __restrict__ e_sq,
                                                         unsigned int* __restrict__ cand_count,
                                                         unsigned int* __restrict__ cands,
                                                         int slots) {
    __shared__ float xs[BD][BN];
    __shared__ float es[BD][BK];
    __shared__ float bbest[BN];
    __shared__ unsigned long long smin[BN][33];

    const int tid = threadIdx.x;
    const int tx = tid & 31, ty = tid >> 5;
    const int kb = blockIdx.x * BK;
    const int nb = blockIdx.y * BN;

    float acc[8][8];
#pragma unroll
    for (int i = 0; i < 8; ++i)
#pragma unroll
        for (int j = 0; j < 8; ++j) acc[i][j] = 0.f;

    for (int dt = 0; dt < DIM; dt += BD) {
        {
            int row = tid >> 2, seg = tid & 3;
            const float* xp = x + (size_t)(nb + row) * DIM + dt + seg * 4;
            float4 v0 = *(const float4*)(xp);
            float4 v1 = *(const float4*)(xp + 16);
            xs[seg * 4 + 0][row] = v0.x;  xs[seg * 4 + 1][row] = v0.y;
            xs[seg * 4 + 2][row] = v0.z;  xs[seg * 4 + 3][row] = v0.w;
            xs[seg * 4 + 16][row] = v1.x; xs[seg * 4 + 17][row] = v1.y;
            xs[seg * 4 + 18][row] = v1.z; xs[seg * 4 + 19][row] = v1.w;
        }
        {
            const float* ep = embed + (size_t)(kb + tid) * DIM + dt;
            float4 v[8];
#pragma unroll
            for (int i = 0; i < 8; ++i) v[i] = *(const float4*)(ep + i * 4);
#pragma unroll
            for (int i = 0; i < 8; ++i) {
                es[i * 4 + 0][tid] = v[i].x; es[i * 4 + 1][tid] = v[i].y;
                es[i * 4 + 2][tid] = v[i].z; es[i * 4 + 3][tid] = v[i].w;
            }
        }
        __syncthreads();
#pragma unroll
        for (int d = 0; d < BD; ++d) {
            float a[8], b[8];
            float4 a0 = *(const float4*)&xs[d][ty * 8];
            float4 a1 = *(const float4*)&xs[d][ty * 8 + 4];
            a[0] = a0.x; a[1] = a0.y; a[2] = a0.z; a[3] = a0.w;
            a[4] = a1.x; a[5] = a1.y; a[6] = a1.z; a[7] = a1.w;
#pragma unroll
            for (int j = 0; j < 8; ++j) b[j] = es[d][tx + j * 32];
#pragma unroll
            for (int i = 0; i < 8; ++i)
#pragma unroll
                for (int j = 0; j < 8; ++j) acc[i][j] = fmaf(a[i], b[j], acc[i][j]);
        }
        __syncthreads();
    }

    float esr[8];
#pragma unroll
    for (int j = 0; j < 8; ++j) esr[j] = e_sq[kb + tx + j * 32];
#pragma unroll
    for (int i = 0; i < 8; ++i) {
        float best = 3.4e38f;
#pragma unroll
        for (int j = 0; j < 8; ++j) {
            acc[i][j] = fmaf(-2.f, acc[i][j], esr[j]);
            if (acc[i][j] < best) best = acc[i][j];
        }
        smin[ty * 8 + i][tx] = ((unsigned long long)ord_f32(best) << 32);
    }
    __syncthreads();
    if (tid < BN) {
        unsigned long long m = smin[tid][0];
#pragma unroll 4
        for (int c = 1; c < 32; ++c) {
            unsigned long long v = smin[tid][c];
            if (v < m) m = v;
        }
        bbest[tid] = unord_f32((unsigned int)(m >> 32));
    }
    __syncthreads();
#pragma unroll
    for (int i = 0; i < 8; ++i) {
        int row = ty * 8 + i;
        float thr = bbest[row] + EPS_MFMA;
#pragma unroll
        for (int j = 0; j < 8; ++j) {
            if (acc[i][j] <= thr) {
                unsigned int slot = atomicAdd(&cand_count[nb + row], 1u);
                if (slot < (unsigned)slots)
                    cands[(size_t)(nb + row) * slots + slot] =
                        (ord_f32(acc[i][j]) & 0xFFFFE000u) | (unsigned)(kb + tx + j * 32);
            }
        }
    }
}

// ---------------------------------------------------------------- pass B: key-filter + f64 survivor re-score + gather + STE + loss
__global__ __launch_bounds__(256) void refine_kernel(const float* __restrict__ x,
                                                     const float* __restrict__ embed,
                                                     const unsigned int* __restrict__ cand_count,
                                                     const unsigned int* __restrict__ cands,
                                                     int slots,
                                                     float* __restrict__ out_q,
                                                     float* __restrict__ out_ind,
                                                     double* __restrict__ loss_acc) {
    __shared__ double s_score[64];
    __shared__ unsigned int s_idx[64];
    __shared__ unsigned int s_minkey;
    __shared__ int s_ns;
    __shared__ int s_best;
    __shared__ float s_ls[4];

    const int row = blockIdx.x;
    const int tid = threadIdx.x;
    const int wave = tid >> 6, lane = tid & 63;
    const unsigned int craw = cand_count[row];
    const float4* xp = (const float4*)(x + (size_t)row * DIM);

    if (craw <= (unsigned)slots) {
        int c = (int)craw;
        if (c < 1) c = 1;
        // min packed key via wave 0 (c <= 64)
        if (tid < 64) {
            unsigned int k = (tid < c) ? cands[(size_t)row * slots + tid] : 0xFFFFFFFFu;
#pragma unroll
            for (int d = 1; d < 64; d <<= 1) {
                unsigned int o = (unsigned int)__shfl_xor((int)k, d);
                if (o < k) k = o;
            }
            if (tid == 0) { s_minkey = k; s_ns = 0; }
        }
        __syncthreads();
        const float th = unord_f32(s_minkey & 0xFFFFE000u) + EPS_MFMA + QMARG;
        if (tid < c) {
            unsigned int k = cands[(size_t)row * slots + tid];
            if (unord_f32(k & 0xFFFFE000u) <= th) {
                int sl = atomicAdd(&s_ns, 1);
                s_idx[sl] = k & 0x1FFFu;
            }
        }
        __syncthreads();
        const int ns = s_ns;
        for (int ci = wave; ci < ns; ci += 4) {
            unsigned int k = s_idx[ci];
            const float4* ep = (const float4*)(embed + (size_t)k * DIM);
            double s = 0.0;
#pragma unroll
            for (int i = 0; i < 2; ++i) {
                float4 ev = ep[lane + i * 64];
                float4 xv = xp[lane + i * 64];
                s += (double)ev.x * ((double)ev.x - 2.0 * (double)xv.x);
                s += (double)ev.y * ((double)ev.y - 2.0 * (double)xv.y);
                s += (double)ev.z * ((double)ev.z - 2.0 * (double)xv.z);
                s += (double)ev.w * ((double)ev.w - 2.0 * (double)xv.w);
            }
#pragma unroll
            for (int off = 32; off > 0; off >>= 1) s += __shfl_down(s, off);
            if (lane == 0) s_score[ci] = s;
        }
        __syncthreads();
        if (tid == 0) {
            double best = s_score[0];
            unsigned int bidx = s_idx[0];
            for (int ci = 1; ci < ns; ++ci) {
                double sv = s_score[ci];
                unsigned int k = s_idx[ci];
                if (sv < best || (sv == best && k < bidx)) { best = sv; bidx = k; }
            }
            s_best = (int)bidx;
            out_ind[row] = (float)bidx;
        }
    } else {
        // overflow safety net: exact f64 scan over all codes
        double wbest = 1e300;
        int wbidx = 0;
        for (int k = wave; k < K_CODES; k += 4) {
            const float4* ep = (const float4*)(embed + (size_t)k * DIM);
            double s = 0.0;
#pragma unroll
            for (int i = 0; i < 2; ++i) {
                float4 ev = ep[lane + i * 64];
                float4 xv = xp[lane + i * 64];
                s += (double)ev.x * ((double)ev.x - 2.0 * (double)xv.x);
                s += (double)ev.y * ((double)ev.y - 2.0 * (double)xv.y);
                s += (double)ev.z * ((double)ev.z - 2.0 * (double)xv.z);
                s += (double)ev.w * ((double)ev.w - 2.0 * (double)xv.w);
            }
#pragma unroll
            for (int off = 32; off > 0; off >>= 1) s += __shfl_down(s, off);
            if (lane == 0 && s < wbest) { wbest = s; wbidx = k; }
        }
        if (lane == 0) { s_score[wave] = wbest; s_idx[wave] = (unsigned)wbidx; }
        __syncthreads();
        if (tid == 0) {
            double best = s_score[0];
            unsigned int bidx = s_idx[0];
            for (int w = 1; w < 4; ++w) {
                if (s_score[w] < best || (s_score[w] == best && s_idx[w] < bidx)) {
                    best = s_score[w]; bidx = s_idx[w];
                }
            }
            s_best = (int)bidx;
            out_ind[row] = (float)bidx;
        }
    }
    __syncthreads();
    const int k = s_best;
    const float2* x2 = (const float2*)(x + (size_t)row * DIM);
    const float2* e2 = (const float2*)(embed + (size_t)k * DIM);
    float2* o2 = (float2*)(out_q + (size_t)row * DIM);
    float2 xv = x2[tid], ev = e2[tid];
    float2 o;
    o.x = xv.x + (ev.x - xv.x);
    o.y = xv.y + (ev.y - xv.y);
    o2[tid] = o;
    float dx = ev.x - xv.x, dy = ev.y - xv.y;
    float ls = dx * dx + dy * dy;
#pragma unroll
    for (int off = 32; off > 0; off >>= 1) ls += __shfl_down(ls, off);
    if (lane == 0) s_ls[wave] = ls;
    __syncthreads();
    if (tid == 0) atomicAdd(loss_acc, (double)(s_ls[0] + s_ls[1] + s_ls[2] + s_ls[3]));
}

// ---------------------------------------------------------------- finalize loss
__global__ void finalize_kernel(const double* __restrict__ loss_acc, float* __restrict__ out_loss) {
    *out_loss = (float)(*loss_acc / ((double)N_ROWS * (double)DIM));
}

// ---------------------------------------------------------------- launch
extern "C" void kernel_launch(void* const* d_in, const int* in_sizes, int n_in,
                              void* d_out, int out_size, void* d_ws, size_t ws_size,
                              hipStream_t stream) {
    const float* x = (const float*)d_in[0];
    const float* embed = (const float*)d_in[1];
    float* out = (float*)d_out;
    float* out_q = out;
    float* out_ind = out + (size_t)N_ROWS * DIM;
    float* out_loss = out_ind + N_ROWS;

    char* ws = (char*)d_ws;
    double* loss_acc = (double*)ws;                                   // 16 B
    float* e_sq = (float*)(ws + 16);                                  // 32 KB
    unsigned int* counts = (unsigned int*)(ws + 16 + 32768);          // 128 KB
    char* dyn = ws + 16 + 32768 + 131072;
    size_t fixed = (size_t)16 + 32768 + 131072;
    size_t dyn_avail = ws_size > fixed ? ws_size - fixed : 0;

    const size_t xbf_b = (size_t)N_ROWS * DIM * 2;   // 33.5 MB
    const size_t ebf_b = (size_t)K_CODES * DIM * 2;  // 8.4 MB
    const size_t need_mfma = xbf_b + ebf_b + (size_t)N_ROWS * SLOTS * 4;

    hipMemsetAsync(counts, 0, (size_t)N_ROWS * 4, stream);
    hipMemsetAsync(loss_acc, 0, 16, stream);
    esq_kernel<<<K_CODES / 4, 256, 0, stream>>>(embed, e_sq);

    if (dyn_avail >= need_mfma) {
        unsigned short* xbf = (unsigned short*)dyn;
        unsigned short* ebf = (unsigned short*)(dyn + xbf_b);
        unsigned int* cands = (unsigned int*)(dyn + xbf_b + ebf_b);
        cvt_kernel<<<(N_ROWS * DIM / 8 + 255) / 256, 256, 0, stream>>>(x, xbf, N_ROWS * DIM / 8);
        cvt_kernel<<<(K_CODES * DIM / 8 + 255) / 256, 256, 0, stream>>>(embed, ebf, K_CODES * DIM / 8);
        passA2_kernel<<<dim3(K_CODES / TN2, N_ROWS / TM2), 512, 0, stream>>>(xbf, ebf, e_sq, counts, cands);
        refine_kernel<<<N_ROWS, 256, 0, stream>>>(x, embed, counts, cands, SLOTS, out_q, out_ind, loss_acc);
    } else {
        unsigned int* cands = (unsigned int*)dyn;
        int slots = 40;
        size_t avail = dyn_avail / ((size_t)N_ROWS * 4);
        if (avail < (size_t)slots) slots = (int)avail;
        if (slots < 2) slots = 2;
        passA_fp32_kernel<<<dim3(K_CODES / BK, N_ROWS / BN), 256, 0, stream>>>(x, embed, e_sq, counts, cands, slots);
        refine_kernel<<<N_ROWS, 256, 0, stream>>>(x, embed, counts, cands, slots, out_q, out_ind, loss_acc);
    }
    finalize_kernel<<<1, 1, 0, stream>>>(loss_acc, out_loss);
}

// Round 4
// 810.325 us; speedup vs baseline: 8.6434x; 1.4385x over previous
//
#include <hip/hip_runtime.h>

#define N_ROWS 32768
#define DIM 512
#define K_CODES 8192

// ---- MFMA pass geometry: 256x256 tile, BK=32, 8 waves, double-buffered
#define TM2 256
#define TN2 256
#define BK2 32
#define NKT (DIM / BK2)      // 16 K-tiles
#define EPS_MFMA 1.5f
#define QMARG 2.2f           // covers 19-bit score quantization (step <= 2.0 for scores < 4096)
#define SLOTS 48

// ---- fp32 fallback geometry
#define BN 64
#define BK 256
#define BD 32

typedef __attribute__((ext_vector_type(8))) short bf16x8;
typedef __attribute__((ext_vector_type(4))) float f32x4;
typedef __attribute__((ext_vector_type(8))) unsigned short ushort8;

__device__ inline unsigned int ord_f32(float f) {
    unsigned int u = __float_as_uint(f);
    return (u & 0x80000000u) ? ~u : (u | 0x80000000u);
}
__device__ inline float unord_f32(unsigned int u) {
    unsigned int b = (u & 0x80000000u) ? (u & 0x7fffffffu) : ~u;
    return __uint_as_float(b);
}
__device__ inline unsigned short f2bf_rn(float f) {
    unsigned int u = __float_as_uint(f);
    u += 0x7fffu + ((u >> 16) & 1u);
    return (unsigned short)(u >> 16);
}

// ---------------------------------------------------------------- e_sq
__global__ __launch_bounds__(256) void esq_kernel(const float* __restrict__ embed,
                                                  float* __restrict__ e_sq) {
    int code = blockIdx.x * 4 + (threadIdx.x >> 6);
    int lane = threadIdx.x & 63;
    const float4* row = (const float4*)(embed + (size_t)code * DIM);
    float s = 0.f;
#pragma unroll
    for (int i = 0; i < 2; ++i) {
        float4 v = row[lane + i * 64];
        s += v.x * v.x + v.y * v.y + v.z * v.z + v.w * v.w;
    }
#pragma unroll
    for (int off = 32; off > 0; off >>= 1) s += __shfl_down(s, off);
    if (lane == 0) e_sq[code] = s;
}

// ---------------------------------------------------------------- fp32 -> bf16
__global__ __launch_bounds__(256) void cvt_kernel(const float* __restrict__ in,
                                                  unsigned short* __restrict__ out, int n8) {
    int i = blockIdx.x * 256 + threadIdx.x;
    if (i >= n8) return;
    const float4* p = (const float4*)in;
    float4 v0 = p[(size_t)i * 2], v1 = p[(size_t)i * 2 + 1];
    ushort8 o;
    o[0] = f2bf_rn(v0.x); o[1] = f2bf_rn(v0.y); o[2] = f2bf_rn(v0.z); o[3] = f2bf_rn(v0.w);
    o[4] = f2bf_rn(v1.x); o[5] = f2bf_rn(v1.y); o[6] = f2bf_rn(v1.z); o[7] = f2bf_rn(v1.w);
    ((ushort8*)out)[i] = o;
}

// ---------------------------------------------------------------- pass A: 256x256 counted-vmcnt dbuf MFMA GEMM + candidate emission
// LDS k-quarter swizzle (both-sides, rule #21): chunk c holds global quarter
// (c&3)^((c>>3)&3); reader uses slot = l4 ^ ((row>>1)&3). Spreads ds_read_b128
// across all 8 16B-granule positions per 2-row span -> 2-way (free) conflicts.
__global__ __launch_bounds__(512) void passA2_kernel(const unsigned short* __restrict__ xbf,
                                                     const unsigned short* __restrict__ ebf,
                                                     const float* __restrict__ e_sq,
                                                     unsigned int* __restrict__ cand_count,
                                                     unsigned int* __restrict__ cands) {
    __shared__ __align__(16) unsigned short As[2][TM2 * BK2];  // 2 x 16 KB
    __shared__ __align__(16) unsigned short Bs[2][TN2 * BK2];  // 2 x 16 KB

    const int tid = threadIdx.x;
    const int lane = tid & 63;
    const int wv = tid >> 6;              // 8 waves: 2 (M) x 4 (N)
    const int wm = wv >> 2, wn = wv & 3;
    const int l15 = lane & 15, l4 = lane >> 4;      // l4 in 0..3 = k-quarter
    const int slot = l4 ^ ((l15 >> 1) & 3);         // swizzled LDS quarter
    const int row0 = blockIdx.y * TM2;
    const int col0 = blockIdx.x * TN2;

    // staging chunk map: chunk c -> row c>>2, swizzled global quarter, LDS byte c*16 (linear)
    const int c0 = tid, c1 = tid + 512;
    const int q0 = ((c0 & 3) ^ ((c0 >> 3) & 3)) * 8;
    const int q1 = ((c1 & 3) ^ ((c1 >> 3) & 3)) * 8;
    const unsigned short* xr0 = xbf + (size_t)(row0 + (c0 >> 2)) * DIM + q0;
    const unsigned short* xr1 = xbf + (size_t)(row0 + (c1 >> 2)) * DIM + q1;
    const unsigned short* er0 = ebf + (size_t)(col0 + (c0 >> 2)) * DIM + q0;
    const unsigned short* er1 = ebf + (size_t)(col0 + (c1 >> 2)) * DIM + q1;

    f32x4 acc[8][4];
#pragma unroll
    for (int m = 0; m < 8; ++m)
#pragma unroll
        for (int n = 0; n < 4; ++n) acc[m][n] = f32x4{0.f, 0.f, 0.f, 0.f};

#define STAGE(buf, kt)                                                                              \
    do {                                                                                            \
        __builtin_amdgcn_global_load_lds((const __attribute__((address_space(1))) void*)(xr0 + (kt)),\
                                         (__attribute__((address_space(3))) void*)&As[buf][c0 * 8], 16, 0, 0); \
        __builtin_amdgcn_global_load_lds((const __attribute__((address_space(1))) void*)(xr1 + (kt)),\
                                         (__attribute__((address_space(3))) void*)&As[buf][c1 * 8], 16, 0, 0); \
        __builtin_amdgcn_global_load_lds((const __attribute__((address_space(1))) void*)(er0 + (kt)),\
                                         (__attribute__((address_space(3))) void*)&Bs[buf][c0 * 8], 16, 0, 0); \
        __builtin_amdgcn_global_load_lds((const __attribute__((address_space(1))) void*)(er1 + (kt)),\
                                         (__attribute__((address_space(3))) void*)&Bs[buf][c1 * 8], 16, 0, 0); \
    } while (0)

    STAGE(0, 0);
    int buf = 0;
    for (int kt = 0; kt < NKT; ++kt) {
        if (kt + 1 < NKT) {
            STAGE(buf ^ 1, (kt + 1) * BK2);
            // T4: keep the 4 just-issued loads in flight; wait only for current buf's 4
            asm volatile("s_waitcnt vmcnt(4)" ::: "memory");
        } else {
            asm volatile("s_waitcnt vmcnt(0)" ::: "memory");
        }
        __builtin_amdgcn_s_barrier();   // all waves' stages for buf visible
        bf16x8 af[8], bfr[4];
#pragma unroll
        for (int m = 0; m < 8; ++m)
            af[m] = *(const bf16x8*)&As[buf][(wm * 128 + m * 16 + l15) * BK2 + slot * 8];
#pragma unroll
        for (int n = 0; n < 4; ++n)
            bfr[n] = *(const bf16x8*)&Bs[buf][(wn * 64 + n * 16 + l15) * BK2 + slot * 8];
#pragma unroll
        for (int m = 0; m < 8; ++m)
#pragma unroll
            for (int n = 0; n < 4; ++n)
                acc[m][n] = __builtin_amdgcn_mfma_f32_16x16x32_bf16(af[m], bfr[n], acc[m][n], 0, 0, 0);
        asm volatile("s_waitcnt lgkmcnt(0)" ::: "memory");
        __builtin_amdgcn_sched_barrier(0);
        __builtin_amdgcn_s_barrier();   // all waves done reading buf before it is re-staged
        buf ^= 1;
    }
#undef STAGE

    // ---- epilogue (once per block). As is dead now -> alias row_min onto it.
    unsigned int* row_min = (unsigned int*)&As[0][0];

    float esr[4];
#pragma unroll
    for (int n = 0; n < 4; ++n) esr[n] = e_sq[col0 + wn * 64 + n * 16 + l15];

    float rv[8][4];
#pragma unroll
    for (int m = 0; m < 8; ++m)
#pragma unroll
        for (int r = 0; r < 4; ++r) rv[m][r] = 3.4e38f;
#pragma unroll
    for (int m = 0; m < 8; ++m)
#pragma unroll
        for (int n = 0; n < 4; ++n)
#pragma unroll
            for (int r = 0; r < 4; ++r) {
                float s = fmaf(-2.f, acc[m][n][r], esr[n]);
                acc[m][n][r] = s;
                rv[m][r] = fminf(rv[m][r], s);
            }
#pragma unroll
    for (int d = 1; d < 16; d <<= 1)
#pragma unroll
        for (int m = 0; m < 8; ++m)
#pragma unroll
            for (int r = 0; r < 4; ++r) rv[m][r] = fminf(rv[m][r], __shfl_xor(rv[m][r], d));

    if (tid < TM2) row_min[tid] = 0xFFFFFFFFu;
    __syncthreads();
    if (l15 == 0) {
#pragma unroll
        for (int m = 0; m < 8; ++m)
#pragma unroll
            for (int r = 0; r < 4; ++r)
                atomicMin(&row_min[wm * 128 + m * 16 + l4 * 4 + r], ord_f32(rv[m][r]));
    }
    __syncthreads();
#pragma unroll
    for (int m = 0; m < 8; ++m)
#pragma unroll
        for (int r = 0; r < 4; ++r) {
            const int lrow = wm * 128 + m * 16 + l4 * 4 + r;
            const float th = unord_f32(row_min[lrow]) + EPS_MFMA;
            const int grow = row0 + lrow;
#pragma unroll
            for (int n = 0; n < 4; ++n) {
                if (acc[m][n][r] <= th) {
                    unsigned int s = atomicAdd(&cand_count[grow], 1u);
                    if (s < SLOTS) {
                        unsigned int code = (unsigned)(col0 + wn * 64 + n * 16 + l15);
                        cands[(size_t)grow * SLOTS + s] =
                            (ord_f32(acc[m][n][r]) & 0xFFFFE000u) | code;
                    }
                }
            }
        }
}

// ---------------------------------------------------------------- fp32 fallback pass A
__global__ __launch_bounds__(256) void passA_fp32_kernel(const float* __restrict__ x,
                                                         const float* __restrict__ embed,
                                                         const float* __restrict__ e_sq,
                                                         unsigned int* __restrict__ cand_count,
                                                         unsigned int* __restrict__ cands,
                                                         int slots) {
    __shared__ float xs[BD][BN];
    __shared__ float es[BD][BK];
    __shared__ float bbest[BN];
    __shared__ unsigned long long smin[BN][33];

    const int tid = threadIdx.x;
    const int tx = tid & 31, ty = tid >> 5;
    const int kb = blockIdx.x * BK;
    const int nb = blockIdx.y * BN;

    float acc[8][8];
#pragma unroll
    for (int i = 0; i < 8; ++i)
#pragma unroll
        for (int j = 0; j < 8; ++j) acc[i][j] = 0.f;

    for (int dt = 0; dt < DIM; dt += BD) {
        {
            int row = tid >> 2, seg = tid & 3;
            const float* xp = x + (size_t)(nb + row) * DIM + dt + seg * 4;
            float4 v0 = *(const float4*)(xp);
            float4 v1 = *(const float4*)(xp + 16);
            xs[seg * 4 + 0][row] = v0.x;  xs[seg * 4 + 1][row] = v0.y;
            xs[seg * 4 + 2][row] = v0.z;  xs[seg * 4 + 3][row] = v0.w;
            xs[seg * 4 + 16][row] = v1.x; xs[seg * 4 + 17][row] = v1.y;
            xs[seg * 4 + 18][row] = v1.z; xs[seg * 4 + 19][row] = v1.w;
        }
        {
            const float* ep = embed + (size_t)(kb + tid) * DIM + dt;
            float4 v[8];
#pragma unroll
            for (int i = 0; i < 8; ++i) v[i] = *(const float4*)(ep + i * 4);
#pragma unroll
            for (int i = 0; i < 8; ++i) {
                es[i * 4 + 0][tid] = v[i].x; es[i * 4 + 1][tid] = v[i].y;
                es[i * 4 + 2][tid] = v[i].z; es[i * 4 + 3][tid] = v[i].w;
            }
        }
        __syncthreads();
#pragma unroll
        for (int d = 0; d < BD; ++d) {
            float a[8], b[8];
            float4 a0 = *(const float4*)&xs[d][ty * 8];
            float4 a1 = *(const float4*)&xs[d][ty * 8 + 4];
            a[0] = a0.x; a[1] = a0.y; a[2] = a0.z; a[3] = a0.w;
            a[4] = a1.x; a[5] = a1.y; a[6] = a1.z; a[7] = a1.w;
#pragma unroll
            for (int j = 0; j < 8; ++j) b[j] = es[d][tx + j * 32];
#pragma unroll
            for (int i = 0; i < 8; ++i)
#pragma unroll
                for (int j = 0; j < 8; ++j) acc[i][j] = fmaf(a[i], b[j], acc[i][j]);
        }
        __syncthreads();
    }

    float esr[8];
#pragma unroll
    for (int j = 0; j < 8; ++j) esr[j] = e_sq[kb + tx + j * 32];
#pragma unroll
    for (int i = 0; i < 8; ++i) {
        float best = 3.4e38f;
#pragma unroll
        for (int j = 0; j < 8; ++j) {
            acc[i][j] = fmaf(-2.f, acc[i][j], esr[j]);
            if (acc[i][j] < best) best = acc[i][j];
        }
        smin[ty * 8 + i][tx] = ((unsigned long long)ord_f32(best) << 32);
    }
    __syncthreads();
    if (tid < BN) {
        unsigned long long m = smin[tid][0];
#pragma unroll 4
        for (int c = 1; c < 32; ++c) {
            unsigned long long v = smin[tid][c];
            if (v < m) m = v;
        }
        bbest[tid] = unord_f32((unsigned int)(m >> 32));
    }
    __syncthreads();
#pragma unroll
    for (int i = 0; i < 8; ++i) {
        int row = ty * 8 + i;
        float thr = bbest[row] + EPS_MFMA;
#pragma unroll
        for (int j = 0; j < 8; ++j) {
            if (acc[i][j] <= thr) {
                unsigned int slot = atomicAdd(&cand_count[nb + row], 1u);
                if (slot < (unsigned)slots)
                    cands[(size_t)(nb + row) * slots + slot] =
                        (ord_f32(acc[i][j]) & 0xFFFFE000u) | (unsigned)(kb + tx + j * 32);
            }
        }
    }
}

// ---------------------------------------------------------------- pass B: key-filter + f64 survivor re-score + gather + STE + per-row loss partial
__global__ __launch_bounds__(256) void refine_kernel(const float* __restrict__ x,
                                                     const float* __restrict__ embed,
                                                     const unsigned int* __restrict__ cand_count,
                                                     const unsigned int* __restrict__ cands,
                                                     int slots,
                                                     float* __restrict__ out_q,
                                                     float* __restrict__ out_ind,
                                                     double* __restrict__ partials) {
    __shared__ double s_score[64];
    __shared__ unsigned int s_idx[64];
    __shared__ unsigned int s_minkey;
    __shared__ int s_ns;
    __shared__ int s_best;
    __shared__ float s_ls[4];

    const int row = blockIdx.x;
    const int tid = threadIdx.x;
    const int wave = tid >> 6, lane = tid & 63;
    const unsigned int craw = cand_count[row];
    const float4* xp = (const float4*)(x + (size_t)row * DIM);

    if (craw <= (unsigned)slots) {
        int c = (int)craw;
        if (c < 1) c = 1;
        if (tid < 64) {
            unsigned int k = (tid < c) ? cands[(size_t)row * slots + tid] : 0xFFFFFFFFu;
#pragma unroll
            for (int d = 1; d < 64; d <<= 1) {
                unsigned int o = (unsigned int)__shfl_xor((int)k, d);
                if (o < k) k = o;
            }
            if (tid == 0) { s_minkey = k; s_ns = 0; }
        }
        __syncthreads();
        const float th = unord_f32(s_minkey & 0xFFFFE000u) + EPS_MFMA + QMARG;
        if (tid < c) {
            unsigned int k = cands[(size_t)row * slots + tid];
            if (unord_f32(k & 0xFFFFE000u) <= th) {
                int sl = atomicAdd(&s_ns, 1);
                s_idx[sl] = k & 0x1FFFu;
            }
        }
        __syncthreads();
        const int ns = s_ns;
        for (int ci = wave; ci < ns; ci += 4) {
            unsigned int k = s_idx[ci];
            const float4* ep = (const float4*)(embed + (size_t)k * DIM);
            double s = 0.0;
#pragma unroll
            for (int i = 0; i < 2; ++i) {
                float4 ev = ep[lane + i * 64];
                float4 xv = xp[lane + i * 64];
                s += (double)ev.x * ((double)ev.x - 2.0 * (double)xv.x);
                s += (double)ev.y * ((double)ev.y - 2.0 * (double)xv.y);
                s += (double)ev.z * ((double)ev.z - 2.0 * (double)xv.z);
                s += (double)ev.w * ((double)ev.w - 2.0 * (double)xv.w);
            }
#pragma unroll
            for (int off = 32; off > 0; off >>= 1) s += __shfl_down(s, off);
            if (lane == 0) s_score[ci] = s;
        }
        __syncthreads();
        if (tid == 0) {
            double best = s_score[0];
            unsigned int bidx = s_idx[0];
            for (int ci = 1; ci < ns; ++ci) {
                double sv = s_score[ci];
                unsigned int k = s_idx[ci];
                if (sv < best || (sv == best && k < bidx)) { best = sv; bidx = k; }
            }
            s_best = (int)bidx;
            out_ind[row] = (float)bidx;
        }
    } else {
        // overflow safety net: exact f64 scan over all codes
        double wbest = 1e300;
        int wbidx = 0;
        for (int k = wave; k < K_CODES; k += 4) {
            const float4* ep = (const float4*)(embed + (size_t)k * DIM);
            double s = 0.0;
#pragma unroll
            for (int i = 0; i < 2; ++i) {
                float4 ev = ep[lane + i * 64];
                float4 xv = xp[lane + i * 64];
                s += (double)ev.x * ((double)ev.x - 2.0 * (double)xv.x);
                s += (double)ev.y * ((double)ev.y - 2.0 * (double)xv.y);
                s += (double)ev.z * ((double)ev.z - 2.0 * (double)xv.z);
                s += (double)ev.w * ((double)ev.w - 2.0 * (double)xv.w);
            }
#pragma unroll
            for (int off = 32; off > 0; off >>= 1) s += __shfl_down(s, off);
            if (lane == 0 && s < wbest) { wbest = s; wbidx = k; }
        }
        if (lane == 0) { s_score[wave] = wbest; s_idx[wave] = (unsigned)wbidx; }
        __syncthreads();
        if (tid == 0) {
            double best = s_score[0];
            unsigned int bidx = s_idx[0];
            for (int w = 1; w < 4; ++w) {
                if (s_score[w] < best || (s_score[w] == best && s_idx[w] < bidx)) {
                    best = s_score[w]; bidx = s_idx[w];
                }
            }
            s_best = (int)bidx;
            out_ind[row] = (float)bidx;
        }
    }
    __syncthreads();
    const int k = s_best;
    const float2* x2 = (const float2*)(x + (size_t)row * DIM);
    const float2* e2 = (const float2*)(embed + (size_t)k * DIM);
    float2* o2 = (float2*)(out_q + (size_t)row * DIM);
    float2 xv = x2[tid], ev = e2[tid];
    float2 o;
    o.x = xv.x + (ev.x - xv.x);
    o.y = xv.y + (ev.y - xv.y);
    o2[tid] = o;
    float dx = ev.x - xv.x, dy = ev.y - xv.y;
    float ls = dx * dx + dy * dy;
#pragma unroll
    for (int off = 32; off > 0; off >>= 1) ls += __shfl_down(ls, off);
    if (lane == 0) s_ls[wave] = ls;
    __syncthreads();
    // NO same-address global atomic (was ~0.4 ms of L2 RMW serialization) — per-row partial
    if (tid == 0) partials[row] = (double)(s_ls[0] + s_ls[1] + s_ls[2] + s_ls[3]);
}

// ---------------------------------------------------------------- deterministic loss reduce
__global__ __launch_bounds__(1024) void finalize_kernel(const double* __restrict__ partials,
                                                        float* __restrict__ out_loss) {
    __shared__ double sm[1024];
    double s = 0.0;
    for (int i = threadIdx.x; i < N_ROWS; i += 1024) s += partials[i];
    sm[threadIdx.x] = s;
    __syncthreads();
    for (int off = 512; off > 0; off >>= 1) {
        if (threadIdx.x < off) sm[threadIdx.x] += sm[threadIdx.x + off];
        __syncthreads();
    }
    if (threadIdx.x == 0) *out_loss = (float)(sm[0] / ((double)N_ROWS * (double)DIM));
}

// ---------------------------------------------------------------- launch
extern "C" void kernel_launch(void* const* d_in, const int* in_sizes, int n_in,
                              void* d_out, int out_size, void* d_ws, size_t ws_size,
                              hipStream_t stream) {
    const float* x = (const float*)d_in[0];
    const float* embed = (const float*)d_in[1];
    float* out = (float*)d_out;
    float* out_q = out;
    float* out_ind = out + (size_t)N_ROWS * DIM;
    float* out_loss = out_ind + N_ROWS;

    char* ws = (char*)d_ws;
    float* e_sq = (float*)(ws + 16);                                   // 32 KB
    unsigned int* counts = (unsigned int*)(ws + 16 + 32768);           // 128 KB
    double* partials = (double*)(ws + 16 + 32768 + 131072);            // 256 KB
    char* dyn = ws + 16 + 32768 + 131072 + 262144;
    size_t fixed = (size_t)16 + 32768 + 131072 + 262144;
    size_t dyn_avail = ws_size > fixed ? ws_size - fixed : 0;

    const size_t xbf_b = (size_t)N_ROWS * DIM * 2;   // 33.5 MB
    const size_t ebf_b = (size_t)K_CODES * DIM * 2;  // 8.4 MB
    const size_t need_mfma = xbf_b + ebf_b + (size_t)N_ROWS * SLOTS * 4;

    hipMemsetAsync(counts, 0, (size_t)N_ROWS * 4, stream);
    esq_kernel<<<K_CODES / 4, 256, 0, stream>>>(embed, e_sq);

    if (dyn_avail >= need_mfma) {
        unsigned short* xbf = (unsigned short*)dyn;
        unsigned short* ebf = (unsigned short*)(dyn + xbf_b);
        unsigned int* cands = (unsigned int*)(dyn + xbf_b + ebf_b);
        cvt_kernel<<<(N_ROWS * DIM / 8 + 255) / 256, 256, 0, stream>>>(x, xbf, N_ROWS * DIM / 8);
        cvt_kernel<<<(K_CODES * DIM / 8 + 255) / 256, 256, 0, stream>>>(embed, ebf, K_CODES * DIM / 8);
        passA2_kernel<<<dim3(K_CODES / TN2, N_ROWS / TM2), 512, 0, stream>>>(xbf, ebf, e_sq, counts, cands);
        refine_kernel<<<N_ROWS, 256, 0, stream>>>(x, embed, counts, cands, SLOTS, out_q, out_ind, partials);
    } else {
        unsigned int* cands = (unsigned int*)dyn;
        int slots = 40;
        size_t avail = dyn_avail / ((size_t)N_ROWS * 4);
        if (avail < (size_t)slots) slots = (int)avail;
        if (slots < 2) slots = 2;
        passA_fp32_kernel<<<dim3(K_CODES / BK, N_ROWS / BN), 256, 0, stream>>>(x, embed, e_sq, counts, cands, slots);
        refine_kernel<<<N_ROWS, 256, 0, stream>>>(x, embed, counts, cands, slots, out_q, out_ind, partials);
    }
    finalize_kernel<<<1, 1024, 0, stream>>>(partials, out_loss);
}

// Round 5
// 645.593 us; speedup vs baseline: 10.8488x; 1.2552x over previous
//
#include <hip/hip_runtime.h>

#define N_ROWS 32768
#define DIM 512
#define K_CODES 8192

// ---- MFMA pass geometry: 128x256 tile, BK=32, 8 waves (2M x 4N), 2-ring dbuf
#define TM3 128
#define TN3 256
#define BK2 32
#define NKT (DIM / BK2)      // 16 K-tiles
#define EPS_MFMA 1.5f
#define QMARG 2.2f           // covers 19-bit score quantization (step <= 2.0 for scores < 4096)
#define SLOTS 48

// ---- fp32 fallback geometry
#define BN 64
#define BK 256
#define BD 32

typedef __attribute__((ext_vector_type(8))) short bf16x8;
typedef __attribute__((ext_vector_type(4))) float f32x4;
typedef __attribute__((ext_vector_type(8))) unsigned short ushort8;

__device__ inline unsigned int ord_f32(float f) {
    unsigned int u = __float_as_uint(f);
    return (u & 0x80000000u) ? ~u : (u | 0x80000000u);
}
__device__ inline float unord_f32(unsigned int u) {
    unsigned int b = (u & 0x80000000u) ? (u & 0x7fffffffu) : ~u;
    return __uint_as_float(b);
}
__device__ inline unsigned short f2bf_rn(float f) {
    unsigned int u = __float_as_uint(f);
    u += 0x7fffu + ((u >> 16) & 1u);
    return (unsigned short)(u >> 16);
}

// ---------------------------------------------------------------- e_sq
__global__ __launch_bounds__(256) void esq_kernel(const float* __restrict__ embed,
                                                  float* __restrict__ e_sq) {
    int code = blockIdx.x * 4 + (threadIdx.x >> 6);
    int lane = threadIdx.x & 63;
    const float4* row = (const float4*)(embed + (size_t)code * DIM);
    float s = 0.f;
#pragma unroll
    for (int i = 0; i < 2; ++i) {
        float4 v = row[lane + i * 64];
        s += v.x * v.x + v.y * v.y + v.z * v.z + v.w * v.w;
    }
#pragma unroll
    for (int off = 32; off > 0; off >>= 1) s += __shfl_down(s, off);
    if (lane == 0) e_sq[code] = s;
}

// ---------------------------------------------------------------- fp32 -> bf16
__global__ __launch_bounds__(256) void cvt_kernel(const float* __restrict__ in,
                                                  unsigned short* __restrict__ out, int n8) {
    int i = blockIdx.x * 256 + threadIdx.x;
    if (i >= n8) return;
    const float4* p = (const float4*)in;
    float4 v0 = p[(size_t)i * 2], v1 = p[(size_t)i * 2 + 1];
    ushort8 o;
    o[0] = f2bf_rn(v0.x); o[1] = f2bf_rn(v0.y); o[2] = f2bf_rn(v0.z); o[3] = f2bf_rn(v0.w);
    o[4] = f2bf_rn(v1.x); o[5] = f2bf_rn(v1.y); o[6] = f2bf_rn(v1.z); o[7] = f2bf_rn(v1.w);
    ((ushort8*)out)[i] = o;
}

// ---------------------------------------------------------------- pass A: 128x256 counted-vmcnt dbuf MFMA GEMM + candidate emission
// Quarter-swizzle (verified round 4: conflicts -> 0): chunk c holds global
// k-quarter (c&3)^((c>>3)&3); reader slot = l4 ^ ((l15>>1)&3).
// Grid is XCD-chunked: each XCD owns 4 code-columns (1 MB of B, L2-resident).
__global__ __launch_bounds__(512, 4) void passA3_kernel(const unsigned short* __restrict__ xbf,
                                                        const unsigned short* __restrict__ ebf,
                                                        const float* __restrict__ e_sq,
                                                        unsigned int* __restrict__ cand_count,
                                                        unsigned int* __restrict__ cands) {
    __shared__ __align__(16) unsigned short As[2][TM3 * BK2];  // 2 x 8 KB
    __shared__ __align__(16) unsigned short Bs[2][TN3 * BK2];  // 2 x 16 KB

    const int tid = threadIdx.x;
    const int lane = tid & 63;
    const int wv = tid >> 6;              // 8 waves: 2 (M) x 4 (N)
    const int wm = wv >> 2, wn = wv & 3;
    const int l15 = lane & 15, l4 = lane >> 4;
    const int slot = l4 ^ ((l15 >> 1) & 3);

    // XCD-chunked decode: grid = 32 (codes) x 256 (rows) = 8192 blocks
    const int bid = blockIdx.x;
    const int xcd = bid & 7, idx = bid >> 3;
    const int bx = xcd * 4 + (idx >> 8);   // code column 0..31
    const int by = idx & 255;              // row block 0..255
    const int row0 = by * TM3;
    const int col0 = bx * TN3;

    // staging chunks: A = 512 chunks (1/thread), B = 1024 chunks (2/thread)
    const int cA = tid, cB0 = tid, cB1 = tid + 512;
    const int qA = ((cA & 3) ^ ((cA >> 3) & 3)) * 8;
    const int qB0 = ((cB0 & 3) ^ ((cB0 >> 3) & 3)) * 8;
    const int qB1 = ((cB1 & 3) ^ ((cB1 >> 3) & 3)) * 8;
    const unsigned short* xr = xbf + (size_t)(row0 + (cA >> 2)) * DIM + qA;
    const unsigned short* er0 = ebf + (size_t)(col0 + (cB0 >> 2)) * DIM + qB0;
    const unsigned short* er1 = ebf + (size_t)(col0 + (cB1 >> 2)) * DIM + qB1;

    f32x4 acc[4][4];
#pragma unroll
    for (int m = 0; m < 4; ++m)
#pragma unroll
        for (int n = 0; n < 4; ++n) acc[m][n] = f32x4{0.f, 0.f, 0.f, 0.f};

#define STAGE(buf, kt)                                                                              \
    do {                                                                                            \
        __builtin_amdgcn_global_load_lds((const __attribute__((address_space(1))) void*)(xr + (kt)),\
                                         (__attribute__((address_space(3))) void*)&As[buf][cA * 8], 16, 0, 0); \
        __builtin_amdgcn_global_load_lds((const __attribute__((address_space(1))) void*)(er0 + (kt)),\
                                         (__attribute__((address_space(3))) void*)&Bs[buf][cB0 * 8], 16, 0, 0); \
        __builtin_amdgcn_global_load_lds((const __attribute__((address_space(1))) void*)(er1 + (kt)),\
                                         (__attribute__((address_space(3))) void*)&Bs[buf][cB1 * 8], 16, 0, 0); \
    } while (0)

    STAGE(0, 0);
    int buf = 0;
    for (int kt = 0; kt < NKT; ++kt) {
        if (kt + 1 < NKT) {
            STAGE(buf ^ 1, (kt + 1) * BK2);
            asm volatile("s_waitcnt vmcnt(3)" ::: "memory");  // keep next-tile loads in flight
        } else {
            asm volatile("s_waitcnt vmcnt(0)" ::: "memory");
        }
        __builtin_amdgcn_s_barrier();
        bf16x8 bfr[4], af[4];
#pragma unroll
        for (int n = 0; n < 4; ++n)
            bfr[n] = *(const bf16x8*)&Bs[buf][(wn * 64 + n * 16 + l15) * BK2 + slot * 8];
#pragma unroll
        for (int m = 0; m < 4; ++m)
            af[m] = *(const bf16x8*)&As[buf][(wm * 64 + m * 16 + l15) * BK2 + slot * 8];
#pragma unroll
        for (int m = 0; m < 4; ++m)
#pragma unroll
            for (int n = 0; n < 4; ++n)
                acc[m][n] = __builtin_amdgcn_mfma_f32_16x16x32_bf16(af[m], bfr[n], acc[m][n], 0, 0, 0);
        asm volatile("s_waitcnt lgkmcnt(0)" ::: "memory");
        __builtin_amdgcn_sched_barrier(0);
        __builtin_amdgcn_s_barrier();
        buf ^= 1;
    }
#undef STAGE

    // ---- epilogue (once per block). As is dead -> alias row_min.
    unsigned int* row_min = (unsigned int*)&As[0][0];

    float esr[4];
#pragma unroll
    for (int n = 0; n < 4; ++n) esr[n] = e_sq[col0 + wn * 64 + n * 16 + l15];

    if (tid < TM3) row_min[tid] = 0xFFFFFFFFu;
    __syncthreads();
    // fixup + per-row min (streamed per m to limit register pressure)
#pragma unroll
    for (int m = 0; m < 4; ++m) {
        float rv[4];
#pragma unroll
        for (int r = 0; r < 4; ++r) rv[r] = 3.4e38f;
#pragma unroll
        for (int n = 0; n < 4; ++n)
#pragma unroll
            for (int r = 0; r < 4; ++r) {
                float s = fmaf(-2.f, acc[m][n][r], esr[n]);
                acc[m][n][r] = s;
                rv[r] = fminf(rv[r], s);
            }
#pragma unroll
        for (int d = 1; d < 16; d <<= 1)
#pragma unroll
            for (int r = 0; r < 4; ++r) rv[r] = fminf(rv[r], __shfl_xor(rv[r], d));
        if (l15 == 0) {
#pragma unroll
            for (int r = 0; r < 4; ++r)
                atomicMin(&row_min[wm * 64 + m * 16 + l4 * 4 + r], ord_f32(rv[r]));
        }
    }
    __syncthreads();
    // emit candidates within EPS of the block-local per-row min (packed qscore|code)
#pragma unroll
    for (int m = 0; m < 4; ++m)
#pragma unroll
        for (int r = 0; r < 4; ++r) {
            const int lrow = wm * 64 + m * 16 + l4 * 4 + r;
            const float th = unord_f32(row_min[lrow]) + EPS_MFMA;
            const int grow = row0 + lrow;
#pragma unroll
            for (int n = 0; n < 4; ++n) {
                if (acc[m][n][r] <= th) {
                    unsigned int s = atomicAdd(&cand_count[grow], 1u);
                    if (s < SLOTS) {
                        unsigned int code = (unsigned)(col0 + wn * 64 + n * 16 + l15);
                        cands[(size_t)grow * SLOTS + s] =
                            (ord_f32(acc[m][n][r]) & 0xFFFFE000u) | code;
                    }
                }
            }
        }
}

// ---------------------------------------------------------------- fp32 fallback pass A
__global__ __launch_bounds__(256) void passA_fp32_kernel(const float* __restrict__ x,
                                                         const float* __restrict__ embed,
                                                         const float* __restrict__ e_sq,
                                                         unsigned int* __restrict__ cand_count,
                                                         unsigned int* __restrict__ cands,
                                                         int slots) {
    __shared__ float xs[BD][BN];
    __shared__ float es[BD][BK];
    __shared__ float bbest[BN];
    __shared__ unsigned long long smin[BN][33];

    const int tid = threadIdx.x;
    const int tx = tid & 31, ty = tid >> 5;
    const int kb = blockIdx.x * BK;
    const int nb = blockIdx.y * BN;

    float acc[8][8];
#pragma unroll
    for (int i = 0; i < 8; ++i)
#pragma unroll
        for (int j = 0; j < 8; ++j) acc[i][j] = 0.f;

    for (int dt = 0; dt < DIM; dt += BD) {
        {
            int row = tid >> 2, seg = tid & 3;
            const float* xp = x + (size_t)(nb + row) * DIM + dt + seg * 4;
            float4 v0 = *(const float4*)(xp);
            float4 v1 = *(const float4*)(xp + 16);
            xs[seg * 4 + 0][row] = v0.x;  xs[seg * 4 + 1][row] = v0.y;
            xs[seg * 4 + 2][row] = v0.z;  xs[seg * 4 + 3][row] = v0.w;
            xs[seg * 4 + 16][row] = v1.x; xs[seg * 4 + 17][row] = v1.y;
            xs[seg * 4 + 18][row] = v1.z; xs[seg * 4 + 19][row] = v1.w;
        }
        {
            const float* ep = embed + (size_t)(kb + tid) * DIM + dt;
            float4 v[8];
#pragma unroll
            for (int i = 0; i < 8; ++i) v[i] = *(const float4*)(ep + i * 4);
#pragma unroll
            for (int i = 0; i < 8; ++i) {
                es[i * 4 + 0][tid] = v[i].x; es[i * 4 + 1][tid] = v[i].y;
                es[i * 4 + 2][tid] = v[i].z; es[i * 4 + 3][tid] = v[i].w;
            }
        }
        __syncthreads();
#pragma unroll
        for (int d = 0; d < BD; ++d) {
            float a[8], b[8];
            float4 a0 = *(const float4*)&xs[d][ty * 8];
            float4 a1 = *(const float4*)&xs[d][ty * 8 + 4];
            a[0] = a0.x; a[1] = a0.y; a[2] = a0.z; a[3] = a0.w;
            a[4] = a1.x; a[5] = a1.y; a[6] = a1.z; a[7] = a1.w;
#pragma unroll
            for (int j = 0; j < 8; ++j) b[j] = es[d][tx + j * 32];
#pragma unroll
            for (int i = 0; i < 8; ++i)
#pragma unroll
                for (int j = 0; j < 8; ++j) acc[i][j] = fmaf(a[i], b[j], acc[i][j]);
        }
        __syncthreads();
    }

    float esr[8];
#pragma unroll
    for (int j = 0; j < 8; ++j) esr[j] = e_sq[kb + tx + j * 32];
#pragma unroll
    for (int i = 0; i < 8; ++i) {
        float best = 3.4e38f;
#pragma unroll
        for (int j = 0; j < 8; ++j) {
            acc[i][j] = fmaf(-2.f, acc[i][j], esr[j]);
            if (acc[i][j] < best) best = acc[i][j];
        }
        smin[ty * 8 + i][tx] = ((unsigned long long)ord_f32(best) << 32);
    }
    __syncthreads();
    if (tid < BN) {
        unsigned long long m = smin[tid][0];
#pragma unroll 4
        for (int c = 1; c < 32; ++c) {
            unsigned long long v = smin[tid][c];
            if (v < m) m = v;
        }
        bbest[tid] = unord_f32((unsigned int)(m >> 32));
    }
    __syncthreads();
#pragma unroll
    for (int i = 0; i < 8; ++i) {
        int row = ty * 8 + i;
        float thr = bbest[row] + EPS_MFMA;
#pragma unroll
        for (int j = 0; j < 8; ++j) {
            if (acc[i][j] <= thr) {
                unsigned int slot = atomicAdd(&cand_count[nb + row], 1u);
                if (slot < (unsigned)slots)
                    cands[(size_t)(nb + row) * slots + slot] =
                        (ord_f32(acc[i][j]) & 0xFFFFE000u) | (unsigned)(kb + tx + j * 32);
            }
        }
    }
}

// ---------------------------------------------------------------- pass B: key-filter + f64 survivor re-score + gather + STE + per-row loss partial
__global__ __launch_bounds__(256) void refine_kernel(const float* __restrict__ x,
                                                     const float* __restrict__ embed,
                                                     const unsigned int* __restrict__ cand_count,
                                                     const unsigned int* __restrict__ cands,
                                                     int slots,
                                                     float* __restrict__ out_q,
                                                     float* __restrict__ out_ind,
                                                     double* __restrict__ partials) {
    __shared__ double s_score[64];
    __shared__ unsigned int s_idx[64];
    __shared__ unsigned int s_minkey;
    __shared__ int s_ns;
    __shared__ int s_best;
    __shared__ float s_ls[4];

    const int row = blockIdx.x;
    const int tid = threadIdx.x;
    const int wave = tid >> 6, lane = tid & 63;
    const unsigned int craw = cand_count[row];
    const float4* xp = (const float4*)(x + (size_t)row * DIM);

    if (craw <= (unsigned)slots) {
        int c = (int)craw;
        if (c < 1) c = 1;
        if (tid < 64) {
            unsigned int k = (tid < c) ? cands[(size_t)row * slots + tid] : 0xFFFFFFFFu;
#pragma unroll
            for (int d = 1; d < 64; d <<= 1) {
                unsigned int o = (unsigned int)__shfl_xor((int)k, d);
                if (o < k) k = o;
            }
            if (tid == 0) { s_minkey = k; s_ns = 0; }
        }
        __syncthreads();
        const float th = unord_f32(s_minkey & 0xFFFFE000u) + EPS_MFMA + QMARG;
        if (tid < c) {
            unsigned int k = cands[(size_t)row * slots + tid];
            if (unord_f32(k & 0xFFFFE000u) <= th) {
                int sl = atomicAdd(&s_ns, 1);
                s_idx[sl] = k & 0x1FFFu;
            }
        }
        __syncthreads();
        const int ns = s_ns;
        for (int ci = wave; ci < ns; ci += 4) {
            unsigned int k = s_idx[ci];
            const float4* ep = (const float4*)(embed + (size_t)k * DIM);
            double s = 0.0;
#pragma unroll
            for (int i = 0; i < 2; ++i) {
                float4 ev = ep[lane + i * 64];
                float4 xv = xp[lane + i * 64];
                s += (double)ev.x * ((double)ev.x - 2.0 * (double)xv.x);
                s += (double)ev.y * ((double)ev.y - 2.0 * (double)xv.y);
                s += (double)ev.z * ((double)ev.z - 2.0 * (double)xv.z);
                s += (double)ev.w * ((double)ev.w - 2.0 * (double)xv.w);
            }
#pragma unroll
            for (int off = 32; off > 0; off >>= 1) s += __shfl_down(s, off);
            if (lane == 0) s_score[ci] = s;
        }
        __syncthreads();
        if (tid == 0) {
            double best = s_score[0];
            unsigned int bidx = s_idx[0];
            for (int ci = 1; ci < ns; ++ci) {
                double sv = s_score[ci];
                unsigned int k = s_idx[ci];
                if (sv < best || (sv == best && k < bidx)) { best = sv; bidx = k; }
            }
            s_best = (int)bidx;
            out_ind[row] = (float)bidx;
        }
    } else {
        // overflow safety net: exact f64 scan over all codes
        double wbest = 1e300;
        int wbidx = 0;
        for (int k = wave; k < K_CODES; k += 4) {
            const float4* ep = (const float4*)(embed + (size_t)k * DIM);
            double s = 0.0;
#pragma unroll
            for (int i = 0; i < 2; ++i) {
                float4 ev = ep[lane + i * 64];
                float4 xv = xp[lane + i * 64];
                s += (double)ev.x * ((double)ev.x - 2.0 * (double)xv.x);
                s += (double)ev.y * ((double)ev.y - 2.0 * (double)xv.y);
                s += (double)ev.z * ((double)ev.z - 2.0 * (double)xv.z);
                s += (double)ev.w * ((double)ev.w - 2.0 * (double)xv.w);
            }
#pragma unroll
            for (int off = 32; off > 0; off >>= 1) s += __shfl_down(s, off);
            if (lane == 0 && s < wbest) { wbest = s; wbidx = k; }
        }
        if (lane == 0) { s_score[wave] = wbest; s_idx[wave] = (unsigned)wbidx; }
        __syncthreads();
        if (tid == 0) {
            double best = s_score[0];
            unsigned int bidx = s_idx[0];
            for (int w = 1; w < 4; ++w) {
                if (s_score[w] < best || (s_score[w] == best && s_idx[w] < bidx)) {
                    best = s_score[w]; bidx = s_idx[w];
                }
            }
            s_best = (int)bidx;
            out_ind[row] = (float)bidx;
        }
    }
    __syncthreads();
    const int k = s_best;
    const float2* x2 = (const float2*)(x + (size_t)row * DIM);
    const float2* e2 = (const float2*)(embed + (size_t)k * DIM);
    float2* o2 = (float2*)(out_q + (size_t)row * DIM);
    float2 xv = x2[tid], ev = e2[tid];
    float2 o;
    o.x = xv.x + (ev.x - xv.x);
    o.y = xv.y + (ev.y - xv.y);
    o2[tid] = o;
    float dx = ev.x - xv.x, dy = ev.y - xv.y;
    float ls = dx * dx + dy * dy;
#pragma unroll
    for (int off = 32; off > 0; off >>= 1) ls += __shfl_down(ls, off);
    if (lane == 0) s_ls[wave] = ls;
    __syncthreads();
    if (tid == 0) partials[row] = (double)(s_ls[0] + s_ls[1] + s_ls[2] + s_ls[3]);
}

// ---------------------------------------------------------------- deterministic loss reduce
__global__ __launch_bounds__(1024) void finalize_kernel(const double* __restrict__ partials,
                                                        float* __restrict__ out_loss) {
    __shared__ double sm[1024];
    double s = 0.0;
    for (int i = threadIdx.x; i < N_ROWS; i += 1024) s += partials[i];
    sm[threadIdx.x] = s;
    __syncthreads();
    for (int off = 512; off > 0; off >>= 1) {
        if (threadIdx.x < off) sm[threadIdx.x] += sm[threadIdx.x + off];
        __syncthreads();
    }
    if (threadIdx.x == 0) *out_loss = (float)(sm[0] / ((double)N_ROWS * (double)DIM));
}

// ---------------------------------------------------------------- launch
extern "C" void kernel_launch(void* const* d_in, const int* in_sizes, int n_in,
                              void* d_out, int out_size, void* d_ws, size_t ws_size,
                              hipStream_t stream) {
    const float* x = (const float*)d_in[0];
    const float* embed = (const float*)d_in[1];
    float* out = (float*)d_out;
    float* out_q = out;
    float* out_ind = out + (size_t)N_ROWS * DIM;
    float* out_loss = out_ind + N_ROWS;

    char* ws = (char*)d_ws;
    float* e_sq = (float*)(ws + 16);                                   // 32 KB
    unsigned int* counts = (unsigned int*)(ws + 16 + 32768);           // 128 KB
    double* partials = (double*)(ws + 16 + 32768 + 131072);            // 256 KB
    char* dyn = ws + 16 + 32768 + 131072 + 262144;
    size_t fixed = (size_t)16 + 32768 + 131072 + 262144;
    size_t dyn_avail = ws_size > fixed ? ws_size - fixed : 0;

    const size_t xbf_b = (size_t)N_ROWS * DIM * 2;   // 33.5 MB
    const size_t ebf_b = (size_t)K_CODES * DIM * 2;  // 8.4 MB
    const size_t need_mfma = xbf_b + ebf_b + (size_t)N_ROWS * SLOTS * 4;

    hipMemsetAsync(counts, 0, (size_t)N_ROWS * 4, stream);
    esq_kernel<<<K_CODES / 4, 256, 0, stream>>>(embed, e_sq);

    if (dyn_avail >= need_mfma) {
        unsigned short* xbf = (unsigned short*)dyn;
        unsigned short* ebf = (unsigned short*)(dyn + xbf_b);
        unsigned int* cands = (unsigned int*)(dyn + xbf_b + ebf_b);
        cvt_kernel<<<(N_ROWS * DIM / 8 + 255) / 256, 256, 0, stream>>>(x, xbf, N_ROWS * DIM / 8);
        cvt_kernel<<<(K_CODES * DIM / 8 + 255) / 256, 256, 0, stream>>>(embed, ebf, K_CODES * DIM / 8);
        passA3_kernel<<<(K_CODES / TN3) * (N_ROWS / TM3), 512, 0, stream>>>(xbf, ebf, e_sq, counts, cands);
        refine_kernel<<<N_ROWS, 256, 0, stream>>>(x, embed, counts, cands, SLOTS, out_q, out_ind, partials);
    } else {
        unsigned int* cands = (unsigned int*)dyn;
        int slots = 40;
        size_t avail = dyn_avail / ((size_t)N_ROWS * 4);
        if (avail < (size_t)slots) slots = (int)avail;
        if (slots < 2) slots = 2;
        passA_fp32_kernel<<<dim3(K_CODES / BK, N_ROWS / BN), 256, 0, stream>>>(x, embed, e_sq, counts, cands, slots);
        refine_kernel<<<N_ROWS, 256, 0, stream>>>(x, embed, counts, cands, slots, out_q, out_ind, partials);
    }
    finalize_kernel<<<1, 1024, 0, stream>>>(partials, out_loss);
}